// Round 4
// baseline (18520.363 us; speedup 1.0000x reference)
//
#include <hip/hip_runtime.h>

#define HS   512
#define LNUM 4
#define TT   128
#define MMEM 2048
#define FFD  2048
#define NB   256
#define NT   512
#define INV512 (1.0f/512.0f)
#define QSCALE 0.08838834764831845f  // 1/sqrt(128)

// ---------------- workspace layout (float offsets) ----------------
constexpr size_t OFF_K     = 0;                                   // L*M*HS
constexpr size_t OFF_V     = OFF_K     + (size_t)LNUM*MMEM*HS;
constexpr size_t OFF_WCOMB = OFF_V     + (size_t)LNUM*MMEM*HS;    // L*HS*HS
constexpr size_t OFF_WQT   = OFF_WCOMB + (size_t)LNUM*HS*HS;      // L*HS*HS
constexpr size_t OFF_W2T   = OFF_WQT   + (size_t)LNUM*HS*HS;      // L*FF*HS
constexpr size_t OFF_WGC   = OFF_W2T   + (size_t)LNUM*FFD*HS;     // L*FF*HS = (W1 . g2) @ caWo
constexpr size_t OFF_CSA   = OFF_WGC   + (size_t)LNUM*FFD*HS;     // L*HS
constexpr size_t OFF_SQ    = OFF_CSA   + (size_t)LNUM*HS;         // L*HS
constexpr size_t OFF_CBQ   = OFF_SQ    + (size_t)LNUM*HS;         // L*HS
constexpr size_t OFF_SU    = OFF_CBQ   + (size_t)LNUM*HS;         // L*FF  (W1@g2)
constexpr size_t OFF_CF1   = OFF_SU    + (size_t)LNUM*FFD;        // L*FF  (W1@(g2.bo))
constexpr size_t OFF_CF2   = OFF_CF1   + (size_t)LNUM*FFD;        // L*FF  (W1@b2 + ffB1)
// mutable state (memset to 0)
constexpr size_t OFF_STATE = OFF_CF2   + (size_t)LNUM*FFD;
constexpr size_t OFF_Z1    = OFF_STATE;                           // HS
constexpr size_t OFF_Z02   = OFF_Z1    + HS;                      // 2*HS
constexpr size_t OFF_T1G   = OFF_Z02   + 2*HS;                    // HS
constexpr size_t OFF_T2G   = OFF_T1G   + HS;                      // HS
constexpr size_t OFF_YP    = OFF_T2G   + HS;                      // 4*HS planes
constexpr size_t OFF_Y2P   = OFF_YP    + 4*HS;                    // 8*HS planes
constexpr size_t OFF_CTXP  = OFF_Y2P   + 8*HS;                    // 8*HS planes
constexpr size_t OFF_DENS  = OFF_CTXP  + 8*HS;                    // 128 slots
constexpr size_t OFF_S1S   = OFF_DENS  + 128;                     // 32*2 slots
constexpr size_t OFF_S2S   = OFF_S1S   + 64;                      // 32*2 slots
constexpr size_t OFF_CNT   = OFF_S2S   + 64;                      // 8 u32 (t1done, t2done)
constexpr size_t OFF_FLAGS = OFF_CNT   + 8;                       // NB*32 u32
constexpr size_t OFF_REL   = OFF_FLAGS + (size_t)NB*32;           // 32
constexpr size_t WS_TOTAL  = OFF_REL   + 32;

__device__ __forceinline__ float wred(float v) {
#pragma unroll
  for (int m = 32; m; m >>= 1) v += __shfl_xor(v, m);
  return v;
}
__device__ __forceinline__ float sigm(float x) { return 1.0f/(1.0f+__expf(-x)); }

__device__ __forceinline__ float ald(const float* p) {
  return __hip_atomic_load(p, __ATOMIC_RELAXED, __HIP_MEMORY_SCOPE_AGENT);
}
__device__ __forceinline__ void ast(float* p, float v) {
  __hip_atomic_store(p, v, __ATOMIC_RELAXED, __HIP_MEMORY_SCOPE_AGENT);
}

// flag-array grid barrier with prefetch hook overlapping the wait
template <class F>
__device__ __forceinline__ void barrier_pf(unsigned* flags, unsigned* release,
                                           unsigned g, F&& pf) {
  asm volatile("s_waitcnt vmcnt(0)" ::: "memory");
  __syncthreads();
  const int tid = threadIdx.x;
  if (blockIdx.x == 0) {
    pf();
    if (tid >= 1 && tid < NB) {
      unsigned* f = flags + (size_t)tid*32;
      while (__hip_atomic_load(f, __ATOMIC_RELAXED, __HIP_MEMORY_SCOPE_AGENT) != g)
        __builtin_amdgcn_s_sleep(1);
    }
    __syncthreads();
    if (tid == 0)
      __hip_atomic_store(release, g, __ATOMIC_RELAXED, __HIP_MEMORY_SCOPE_AGENT);
  } else {
    if (tid == 0)
      __hip_atomic_store(flags + (size_t)blockIdx.x*32, g, __ATOMIC_RELAXED, __HIP_MEMORY_SCOPE_AGENT);
    pf();
    if (tid == 0) {
      while (__hip_atomic_load(release, __ATOMIC_RELAXED, __HIP_MEMORY_SCOPE_AGENT) != g)
        __builtin_amdgcn_s_sleep(1);
    }
    __syncthreads();
  }
}

// producer: drain stores then bump monotonic counter
__device__ __forceinline__ void bump(unsigned* ctr) {
  asm volatile("s_waitcnt vmcnt(0)" ::: "memory");
  __syncthreads();
  if (threadIdx.x == 0)
    __hip_atomic_fetch_add(ctr, 1u, __ATOMIC_RELAXED, __HIP_MEMORY_SCOPE_AGENT);
}
// consumer: wait until ctr >= tgt (monotonic)
__device__ __forceinline__ void poll_ge(unsigned* ctr, unsigned tgt) {
  if (threadIdx.x == 0) {
    while ((int)(__hip_atomic_load(ctr, __ATOMIC_RELAXED, __HIP_MEMORY_SCOPE_AGENT) - tgt) < 0)
      __builtin_amdgcn_s_sleep(1);
  }
  __syncthreads();
}

// warp0: reduce 32 (sum,sumsq) slots -> sh[o], sh[o+1]
__device__ __forceinline__ void slotred32(const float* slots, float* sh, int o,
                                          int w, int lane) {
  if (w == 0) {
    float a = (lane < 32) ? ald(slots + lane*2) : ald(slots + (lane-32)*2 + 1);
#pragma unroll
    for (int m = 16; m; m >>= 1) a += __shfl_xor(a, m);
    if (lane == 0)  sh[o]   = a;
    if (lane == 32) sh[o+1] = a;
  }
}
// warps 1,2: reduce 128 den slots -> sh_den[4]
__device__ __forceinline__ void denred(const float* dens, float* sh_den,
                                       int w, int lane) {
  if (w == 1 || w == 2) {
    float v = ald(dens + (w-1)*64 + lane);
#pragma unroll
    for (int m = 16; m; m >>= 1) v += __shfl_xor(v, m);
    if ((lane & 31) == 0) sh_den[(w-1)*2 + (lane >> 5)] = v;
  }
}

// ---------------- precompute kernels ----------------

__global__ __launch_bounds__(256) void kv_gemm(
    const float* __restrict__ hist, const float* __restrict__ caWin,
    const float* __restrict__ caBin, float* __restrict__ out, int koff) {
  __shared__ float As[16][64];
  __shared__ float Bs[16][64];
  const int l = blockIdx.z, m0 = blockIdx.x*64, f0 = blockIdx.y*64;
  const int tid = threadIdx.x, tm = tid >> 4, tf = tid & 15;
  float acc[4][4] = {};
  for (int e0 = 0; e0 < HS; e0 += 16) {
#pragma unroll
    for (int it = 0; it < 4; ++it) {
      int idx = tid + it*256, k = idx & 15, mm = idx >> 4;
      As[k][mm] = hist[((size_t)(m0+mm)*LNUM + l)*HS + e0 + k];
      Bs[k][mm] = caWin[((size_t)l*(3*HS) + koff + f0 + mm)*HS + e0 + k];
    }
    __syncthreads();
#pragma unroll
    for (int k = 0; k < 16; ++k) {
      float a[4], b[4];
#pragma unroll
      for (int x = 0; x < 4; ++x) { a[x] = As[k][tm*4+x]; b[x] = Bs[k][tf*4+x]; }
#pragma unroll
      for (int x = 0; x < 4; ++x)
#pragma unroll
        for (int y = 0; y < 4; ++y) acc[x][y] += a[x]*b[y];
    }
    __syncthreads();
  }
#pragma unroll
  for (int x = 0; x < 4; ++x)
#pragma unroll
    for (int y = 0; y < 4; ++y) {
      int m = m0 + tm*4 + x, f = f0 + tf*4 + y;
      out[((size_t)l*MMEM + m)*HS + f] = acc[x][y] + caBin[l*(3*HS) + koff + f];
    }
}

// wcomb[l,f,j] = sum_e saWo[l,f,e] * saWin[l,2HS+e,j]
__global__ __launch_bounds__(256) void wcomb_gemm(
    const float* __restrict__ saWo, const float* __restrict__ saWin, float* __restrict__ wcomb) {
  __shared__ float As[16][64];
  __shared__ float Bs[16][64];
  const int l = blockIdx.z, f0 = blockIdx.x*64, j0 = blockIdx.y*64;
  const int tid = threadIdx.x, tm = tid >> 4, tf = tid & 15;
  float acc[4][4] = {};
  for (int e0 = 0; e0 < HS; e0 += 16) {
#pragma unroll
    for (int it = 0; it < 4; ++it) {
      int idx = tid + it*256;
      { int k = idx & 15, ff = idx >> 4;
        As[k][ff] = saWo[((size_t)l*HS + f0+ff)*HS + e0 + k]; }
      { int jj = idx & 63, k = idx >> 6;
        Bs[k][jj] = saWin[((size_t)l*(3*HS) + 2*HS + e0 + k)*HS + j0 + jj]; }
    }
    __syncthreads();
#pragma unroll
    for (int k = 0; k < 16; ++k) {
      float a[4], b[4];
#pragma unroll
      for (int x = 0; x < 4; ++x) { a[x] = As[k][tm*4+x]; b[x] = Bs[k][tf*4+x]; }
#pragma unroll
      for (int x = 0; x < 4; ++x)
#pragma unroll
        for (int y = 0; y < 4; ++y) acc[x][y] += a[x]*b[y];
    }
    __syncthreads();
  }
#pragma unroll
  for (int x = 0; x < 4; ++x)
#pragma unroll
    for (int y = 0; y < 4; ++y)
      wcomb[(size_t)l*HS*HS + (size_t)(f0+tm*4+x)*HS + (j0+tf*4+y)] = acc[x][y];
}

// WGC[l,k,j] = sum_e ffW1[l,k,e]*g2[l,e]*caWo[l,e,j]
__global__ __launch_bounds__(256) void wgc_gemm(
    const float* __restrict__ ffW1, const float* __restrict__ lnG,
    const float* __restrict__ caWo, float* __restrict__ wgc) {
  __shared__ float As[16][64];
  __shared__ float Bs[16][64];
  const int l = blockIdx.z, f0 = blockIdx.x*64, j0 = blockIdx.y*64;
  const int tid = threadIdx.x, tm = tid >> 4, tf = tid & 15;
  float acc[4][4] = {};
  for (int e0 = 0; e0 < HS; e0 += 16) {
#pragma unroll
    for (int it = 0; it < 4; ++it) {
      int idx = tid + it*256;
      { int k = idx & 15, ff = idx >> 4;
        As[k][ff] = ffW1[((size_t)l*FFD + f0+ff)*HS + e0 + k] * lnG[l*(3*HS) + HS + e0 + k]; }
      { int jj = idx & 63, k = idx >> 6;
        Bs[k][jj] = caWo[((size_t)l*HS + e0 + k)*HS + j0 + jj]; }
    }
    __syncthreads();
#pragma unroll
    for (int k = 0; k < 16; ++k) {
      float a[4], b[4];
#pragma unroll
      for (int x = 0; x < 4; ++x) { a[x] = As[k][tm*4+x]; b[x] = Bs[k][tf*4+x]; }
#pragma unroll
      for (int x = 0; x < 4; ++x)
#pragma unroll
        for (int y = 0; y < 4; ++y) acc[x][y] += a[x]*b[y];
    }
    __syncthreads();
  }
#pragma unroll
  for (int x = 0; x < 4; ++x)
#pragma unroll
    for (int y = 0; y < 4; ++y)
      wgc[(size_t)l*FFD*HS + (size_t)(f0+tm*4+x)*HS + (j0+tf*4+y)] = acc[x][y];
}

__global__ __launch_bounds__(256) void transpose_scale(
    const float* __restrict__ in, size_t inLS, int R, int C,
    const float* __restrict__ g, size_t gLS, float* __restrict__ out, size_t outLS) {
  __shared__ float tile[32][33];
  const int l = blockIdx.z, e0 = blockIdx.x*32, f0 = blockIdx.y*32;
  const int tx = threadIdx.x & 31, ty = threadIdx.x >> 5;
#pragma unroll
  for (int r = 0; r < 32; r += 8)
    tile[ty+r][tx] = in[(size_t)l*inLS + (size_t)(f0+ty+r)*C + e0 + tx];
  __syncthreads();
#pragma unroll
  for (int r = 0; r < 32; r += 8) {
    int e = e0 + ty + r, f = f0 + tx;
    float s = g ? g[(size_t)l*gLS + e] : 1.0f;
    out[(size_t)l*outLS + (size_t)e*R + f] = tile[tx][ty+r] * s;
  }
}

__global__ __launch_bounds__(256) void csa_kernel(
    const float* __restrict__ saWo, const float* __restrict__ sabin,
    const float* __restrict__ sabo, float* __restrict__ csa) {
  const int w = threadIdx.x >> 6, lane = threadIdx.x & 63;
  const int row = blockIdx.x*4 + w;
  const int l = row >> 9, f = row & 511;
  float acc = 0;
#pragma unroll
  for (int k = 0; k < 8; ++k) {
    int e = lane + 64*k;
    acc += saWo[((size_t)l*HS + f)*HS + e] * sabin[l*(3*HS) + 2*HS + e];
  }
  acc = wred(acc);
  if (lane == 0) csa[row] = acc + sabo[l*HS + f];
}

__global__ __launch_bounds__(256) void sqcbq_kernel(
    const float* __restrict__ caWin, const float* __restrict__ caBin,
    const float* __restrict__ lnG, const float* __restrict__ lnB,
    float* __restrict__ sq, float* __restrict__ cbq) {
  const int w = threadIdx.x >> 6, lane = threadIdx.x & 63;
  const int row = blockIdx.x*4 + w;
  const int l = row >> 9, f = row & 511;
  float a1 = 0, a2 = 0;
#pragma unroll
  for (int k = 0; k < 8; ++k) {
    int e = lane + 64*k;
    float wv = caWin[((size_t)l*(3*HS) + f)*HS + e];
    a1 += wv * lnG[l*(3*HS) + e];
    a2 += wv * lnB[l*(3*HS) + e];
  }
  a1 = wred(a1); a2 = wred(a2);
  if (lane == 0) { sq[row] = a1; cbq[row] = a2 + caBin[l*(3*HS) + f]; }
}

// su[l,k]=W1@g2; c1[l,k]=W1@(g2.bo); c2[l,k]=W1@b2 + ffB1
__global__ __launch_bounds__(256) void ffvec_kernel(
    const float* __restrict__ ffW1, const float* __restrict__ ffB1,
    const float* __restrict__ caBo,
    const float* __restrict__ lnG, const float* __restrict__ lnB,
    float* __restrict__ su, float* __restrict__ c1, float* __restrict__ c2) {
  const int w = threadIdx.x >> 6, lane = threadIdx.x & 63;
  const int row = blockIdx.x*4 + w;
  const int l = row >> 11, k = row & 2047;
  float a1 = 0, a2 = 0, a3 = 0;
#pragma unroll
  for (int q = 0; q < 8; ++q) {
    int e = lane + 64*q;
    float wv = ffW1[((size_t)l*FFD + k)*HS + e];
    float g2 = lnG[l*(3*HS) + HS + e];
    a1 += wv * g2;
    a2 += wv * g2 * caBo[l*HS + e];
    a3 += wv * lnB[l*(3*HS) + HS + e];
  }
  a1 = wred(a1); a2 = wred(a2); a3 = wred(a3);
  if (lane == 0) { su[row] = a1; c1[row] = a2; c2[row] = a3 + ffB1[(size_t)l*FFD + k]; }
}

// ---------------- main persistent sequential kernel ----------------

__global__ __launch_bounds__(NT, 2) void seq_kernel(
    const float* __restrict__ x,
    const float* __restrict__ Wx,  const float* __restrict__ bx,
    const float* __restrict__ Wh,  const float* __restrict__ bh,
    const float* __restrict__ caWo, const float* __restrict__ caBo,
    const float* __restrict__ ffW1,
    const float* __restrict__ ffB2,
    const float* __restrict__ lnG,  const float* __restrict__ lnB,
    float* __restrict__ ws, float* __restrict__ out) {
  const float* Kb    = ws + OFF_K;
  const float* Vb    = ws + OFF_V;
  const float* Wcomb = ws + OFF_WCOMB;
  const float* WqT   = ws + OFF_WQT;
  const float* W2T   = ws + OFF_W2T;
  const float* WGC   = ws + OFF_WGC;
  const float* csag  = ws + OFF_CSA;
  const float* sqg   = ws + OFF_SQ;
  const float* cbqg  = ws + OFF_CBQ;
  const float* suv   = ws + OFF_SU;
  const float* cf1   = ws + OFF_CF1;
  const float* cf2   = ws + OFF_CF2;
  float* z1g   = ws + OFF_Z1;
  float* z02g  = ws + OFF_Z02;
  float* t1g   = ws + OFF_T1G;
  float* t2g   = ws + OFF_T2G;
  float* Yp    = ws + OFF_YP;
  float* Y2p   = ws + OFF_Y2P;
  float* ctxP  = ws + OFF_CTXP;
  float* denS  = ws + OFF_DENS;
  float* s1s   = ws + OFF_S1S;
  float* s2s   = ws + OFF_S2S;
  unsigned* t1done = (unsigned*)(ws + OFF_CNT);
  unsigned* t2done = t1done + 1;
  unsigned* bflags = (unsigned*)(ws + OFF_FLAGS);
  unsigned* brel   = (unsigned*)(ws + OFF_REL);

  __shared__ float sh_xin[HS], sh_h[HS], sh_vec[HS], sh_x1g[HS];
  __shared__ float sh_q[128], sh_p[64], sh_aux[16], sh_t1[16];
  __shared__ float sh_red[24], sh_den[4];

  const int bid = blockIdx.x, tid = threadIdx.x;
  const int w = tid >> 6, lane = tid & 63;
  unsigned gen = 1;

  // register-resident recurrent state (per thread = element tid)
  float h0 = 0.f, h1 = 0.f, h2 = 0.f, h3 = 0.f;
  float c0 = 0.f, c1r = 0.f, c2r = 0.f, c3 = 0.f;
  #define HGET(k_) ((k_)==0 ? h0 : (k_)==1 ? h1 : (k_)==2 ? h2 : h3)
  #define CGET(k_) ((k_)==0 ? c0 : (k_)==1 ? c1r : (k_)==2 ? c2r : c3)
  #define HSET(k_, v_) { if((k_)==0) h0=(v_); else if((k_)==1) h1=(v_); else if((k_)==2) h2=(v_); else h3=(v_); }
  #define CSET(k_, v_) { if((k_)==0) c0=(v_); else if((k_)==1) c1r=(v_); else if((k_)==2) c2r=(v_); else c3=(v_); }

  // prefetch register files
  float pZx[8], pZh[8];          // H1 z rows
  float pWc[2][8], pWq[16];      // H23 t1
  float pK[8][2], pV[16];        // H23 attn
  float pCa[2][8];               // H45 t2
  float pW1[2][8], pWG[2][8], pW2[16]; // H45 ff

  auto pfH1 = [&](int l) {
    if (bid < 192) {
      int g, f;
      if (bid < 64) { g = 1; f = bid*8 + w; }
      else { int rowid = (bid-64)*8 + w; g = (rowid < 512) ? 0 : 2; f = rowid & 511; }
      const float* wxr = Wx + (((size_t)l*3 + g)*HS + f)*HS;
      const float* whr = Wh + (((size_t)l*3 + g)*HS + f)*HS;
#pragma unroll
      for (int k = 0; k < 8; ++k) { pZx[k] = wxr[lane+64*k]; pZh[k] = whr[lane+64*k]; }
    }
  };
  auto pfH23 = [&](int l) {
    if (bid < 32) {
#pragma unroll
      for (int rr = 0; rr < 2; ++rr) {
        const float* wr = Wcomb + ((size_t)l*HS + bid*16 + w*2 + rr)*HS;
#pragma unroll
        for (int k = 0; k < 8; ++k) pWc[rr][k] = wr[lane+64*k];
      }
#pragma unroll
      for (int r = 0; r < 16; ++r)
        pWq[r] = WqT[((size_t)l*HS + bid*16 + r)*HS + tid];
    } else if (bid < 160) {
      const int b2 = bid - 32, h = b2 >> 5, mseg = b2 & 31;
#pragma unroll
      for (int rr = 0; rr < 8; ++rr) {
        const float* kr = Kb + ((size_t)l*MMEM + mseg*64 + w*8 + rr)*HS + h*128;
        pK[rr][0] = kr[lane]; pK[rr][1] = kr[lane+64];
      }
#pragma unroll
      for (int ml = 0; ml < 16; ++ml)
        pV[ml] = Vb[((size_t)l*MMEM + mseg*64 + (tid>>7)*16 + ml)*HS + h*128 + (tid & 127)];
    }
  };
  auto pfH45 = [&](int l) {
    if (bid < 32) {
#pragma unroll
      for (int rr = 0; rr < 2; ++rr) {
        const float* wr = caWo + ((size_t)l*HS + bid*16 + w*2 + rr)*HS;
#pragma unroll
        for (int k = 0; k < 8; ++k) pCa[rr][k] = wr[lane+64*k];
      }
    } else if (bid < 160) {
      const int fb = bid - 32;
#pragma unroll
      for (int rr = 0; rr < 2; ++rr) {
        const float* w1r = ffW1 + ((size_t)l*FFD + fb*16 + w*2 + rr)*HS;
        const float* wgr = WGC  + ((size_t)l*FFD + fb*16 + w*2 + rr)*HS;
#pragma unroll
        for (int k = 0; k < 8; ++k) { pW1[rr][k] = w1r[lane+64*k]; pWG[rr][k] = wgr[lane+64*k]; }
      }
#pragma unroll
      for (int r = 0; r < 16; ++r)
        pW2[r] = W2T[((size_t)l*FFD + fb*16 + r)*HS + tid];
    }
  };

  // fused LSTM update for step s-1 (register-local state): all threads
  auto do_update = [&](int ip, float& xn, float& cn) {
    const int j = tid;
    float t2v = ald(t2g + j);
    float z0  = ald(z02g + j);
    float z2  = ald(z02g + HS + j);
    float y2 = 0;
#pragma unroll
    for (int p = 0; p < 8; ++p) y2 += ald(Y2p + p*HS + j);
    slotred32(s2s, sh_red, 16, w, lane);
    __syncthreads();
    float m2 = sh_red[16]*INV512;
    float r2 = rsqrtf(sh_red[17]*INV512 - m2*m2 + 1e-5f);
    float x2 = (t2v-m2)*r2*lnG[(ip*3+1)*HS+j] + lnB[(ip*3+1)*HS+j];
    float t3 = x2 + y2 + ffB2[ip*HS + j];
    float s_ = t3, q_ = t3*t3;
#pragma unroll
    for (int m = 32; m; m >>= 1) { s_ += __shfl_xor(s_, m); q_ += __shfl_xor(q_, m); }
    if (lane == 0) { sh_red[w] = s_; sh_red[8+w] = q_; }
    __syncthreads();
    if (tid == 0) {
      float a = 0, b = 0;
#pragma unroll
      for (int k = 0; k < 8; ++k) { a += sh_red[k]; b += sh_red[8+k]; }
      sh_red[0] = a; sh_red[1] = b;
    }
    __syncthreads();
    float m3 = sh_red[0]*INV512;
    float r3 = rsqrtf(sh_red[1]*INV512 - m3*m3 + 1e-5f);
    float d  = (t3-m3)*r3*lnG[(ip*3+2)*HS+j] + lnB[(ip*3+2)*HS+j];
    float cp = CGET(ip);
    float ft = sigm(cp - d);
    float it = sigm(z0);
    float gt = tanhf(z2);
    cn = ft*cp + it*gt;
    xn = tanhf(cn);
  };

  pfH1(0);

  for (int s = 0; s < TT*LNUM; ++s) {
    const int t = s >> 2, i = s & 3;
    // ---------- H1: update(s-1) [register-local] + all 3 z-gate matvecs + plane zeroing ----------
    {
      float xn = 0.f, cn = 0.f;
      if (s > 0) {
        const int ip = (s-1) & 3;
        if (bid < 192) {
          do_update(ip, xn, cn);
          CSET(ip, cn); HSET(ip, xn);
          if (bid == 0 && ip == 3) out[((s-1)>>2)*HS + tid] = xn;
        }
      }
      if (bid < 192) {
        sh_xin[tid] = (i == 0) ? x[t*HS + tid] : xn;
        sh_h[tid]   = HGET(i);
        __syncthreads();
        int g, f;
        if (bid < 64) { g = 1; f = bid*8 + w; }
        else { int rowid = (bid-64)*8 + w; g = (rowid < 512) ? 0 : 2; f = rowid & 511; }
        float acc = 0;
#pragma unroll
        for (int k = 0; k < 8; ++k) {
          int e = lane + 64*k;
          acc += pZx[k]*sh_xin[e] + pZh[k]*sh_h[e];
        }
        acc = wred(acc);
        if (lane == 0) {
          float val = acc + bx[(i*3+g)*HS + f] + bh[(i*3+g)*HS + f];
          if (g == 1) ast(z1g + f, val);
          else        ast(z02g + (g ? HS : 0) + f, val);
        }
      } else if (bid < 196) {       // zero Y planes (consumed H23(s-1), produced H23(s))
        ast(Yp + (size_t)(bid-192)*HS + tid, 0.f);
      } else if (bid < 204) {       // zero ctx planes (consumed H45(s-1), produced H23(s))
        ast(ctxP + (size_t)(bid-196)*HS + tid, 0.f);
      }
    }
    barrier_pf(bflags, brel, gen, [&]{ pfH23(i); }); ++gen;
    // ---------- H23: t1/Y/stats1 (0-31) -> counter -> attention (32-159); zero Y2 (160-167) ----------
    if (bid < 32) {
      sh_vec[tid] = sigm(ald(z1g + tid));   // f0
      __syncthreads();
#pragma unroll
      for (int rr = 0; rr < 2; ++rr) {
        const int r = w*2 + rr, j = bid*16 + r;
        float acc = 0;
#pragma unroll
        for (int k = 0; k < 8; ++k) acc += pWc[rr][k]*sh_vec[lane + 64*k];
        acc = wred(acc);
        if (lane == 0) {
          float t1v = sh_vec[j] + acc + csag[i*HS + j];
          sh_t1[r] = t1v;
          sh_aux[r] = t1v;
          ast(t1g + j, t1v);
        }
      }
      __syncthreads();
      {
        float yl = 0;
#pragma unroll
        for (int r = 0; r < 16; ++r) yl += sh_aux[r] * pWq[r];
        atomicAdd(&Yp[(size_t)(bid&3)*HS + tid], yl);
      }
      if (w == 0 && lane < 16) {
        float v = sh_aux[lane], s_ = v, q_ = v*v;
#pragma unroll
        for (int m = 8; m; m >>= 1) { s_ += __shfl_xor(s_, m); q_ += __shfl_xor(q_, m); }
        if (lane == 0) { ast(s1s + bid*2, s_); ast(s1s + bid*2 + 1, q_); }
      }
      bump(t1done);
    } else if (bid < 160) {
      const int b2 = bid - 32, h = b2 >> 5, mseg = b2 & 31;
      poll_ge(t1done, 32u*(s+1));
      slotred32(s1s, sh_red, 18, w, lane);
      __syncthreads();
      if (tid < 128) {
        float m1 = sh_red[18]*INV512;
        float r1 = rsqrtf(sh_red[19]*INV512 - m1*m1 + 1e-5f);
        int f = h*128 + tid;
        float Ysum = 0;
#pragma unroll
        for (int p = 0; p < 4; ++p) Ysum += ald(Yp + (size_t)p*HS + f);
        sh_q[tid] = r1*(Ysum - m1*sqg[i*HS + f]) + cbqg[i*HS + f];
      }
      __syncthreads();
#pragma unroll
      for (int rr = 0; rr < 8; ++rr) {
        float acc = sh_q[lane]*pK[rr][0] + sh_q[lane+64]*pK[rr][1];
        acc = wred(acc);
        if (lane == 0) sh_p[w*8 + rr] = __expf(acc * QSCALE);
      }
      __syncthreads();
      {
        const int d = tid & 127, mg = tid >> 7;
        float acc = 0;
#pragma unroll
        for (int ml = 0; ml < 16; ++ml) acc += sh_p[mg*16 + ml] * pV[ml];
        atomicAdd(&ctxP[(size_t)((b2&1)*4 + mg)*HS + h*128 + d], acc);
      }
      if (w == 0) {
        float v = sh_p[lane];
        v = wred(v);
        if (lane == 0) ast(denS + h*32 + mseg, v);
      }
    } else if (bid < 168) {        // zero Y2 planes (consumed H1(s), produced H45(s))
      ast(Y2p + (size_t)(bid-160)*HS + tid, 0.f);
    }
    barrier_pf(bflags, brel, gen, [&]{ pfH45(i); }); ++gen;
    // ---------- H45: t2/stats2 (0-31) -> counter; ff matvec overlapped (32-159) ----------
    if (bid < 32) {
      slotred32(s1s, sh_red, 18, w, lane);
      denred(denS, sh_den, w, lane);
      __syncthreads();
      float m1 = sh_red[18]*INV512;
      float r1 = rsqrtf(sh_red[19]*INV512 - m1*m1 + 1e-5f);
      {
        float c = 0;
#pragma unroll
        for (int p = 0; p < 8; ++p) c += ald(ctxP + (size_t)p*HS + tid);
        sh_vec[tid] = c / sh_den[tid >> 7];
      }
      __syncthreads();
#pragma unroll
      for (int rr = 0; rr < 2; ++rr) {
        const int r = w*2 + rr, j = bid*16 + r;
        float acc = 0;
#pragma unroll
        for (int k = 0; k < 8; ++k) acc += pCa[rr][k]*sh_vec[lane + 64*k];
        acc = wred(acc);
        if (lane == 0) {
          float x1 = (sh_t1[r]-m1)*r1*lnG[(i*3)*HS + j] + lnB[(i*3)*HS + j];
          float t2v = x1 + acc + caBo[i*HS + j];
          ast(t2g + j, t2v);
          sh_aux[r] = t2v;
        }
      }
      __syncthreads();
      if (w == 0 && lane < 16) {
        float v = sh_aux[lane], s_ = v, q_ = v*v;
#pragma unroll
        for (int m = 8; m; m >>= 1) { s_ += __shfl_xor(s_, m); q_ += __shfl_xor(q_, m); }
        if (lane == 0) { ast(s2s + bid*2, s_); ast(s2s + bid*2 + 1, q_); }
      }
      bump(t2done);
    } else if (bid < 160) {
      const int fb = bid - 32;
      float t1v = ald(t1g + tid);
      slotred32(s1s, sh_red, 18, w, lane);
      denred(denS, sh_den, w, lane);
      __syncthreads();
      float m1 = sh_red[18]*INV512;
      float r1 = rsqrtf(sh_red[19]*INV512 - m1*m1 + 1e-5f);
      sh_x1g[tid] = ((t1v - m1)*r1*lnG[(i*3)*HS + tid] + lnB[(i*3)*HS + tid]) * lnG[(i*3+1)*HS + tid];
      {
        float c = 0;
#pragma unroll
        for (int p = 0; p < 8; ++p) c += ald(ctxP + (size_t)p*HS + tid);
        sh_vec[tid] = c / sh_den[tid >> 7];
      }
      __syncthreads();
      float u[2];
#pragma unroll
      for (int rr = 0; rr < 2; ++rr) {
        float a = 0;
#pragma unroll
        for (int k = 0; k < 8; ++k) {
          int e = lane + 64*k;
          a += pW1[rr][k]*sh_x1g[e] + pWG[rr][k]*sh_vec[e];
        }
        u[rr] = wred(a);
      }
      poll_ge(t2done, 32u*(s+1));
      slotred32(s2s, sh_red, 16, w, lane);
      __syncthreads();
      float m2 = sh_red[16]*INV512;
      float r2 = rsqrtf(sh_red[17]*INV512 - m2*m2 + 1e-5f);
      if (lane == 0) {
#pragma unroll
        for (int rr = 0; rr < 2; ++rr) {
          int row = fb*16 + w*2 + rr;
          float ffv = fmaxf(r2*(u[rr] + cf1[i*FFD + row] - m2*suv[i*FFD + row]) + cf2[i*FFD + row], 0.f);
          sh_aux[w*2 + rr] = ffv;
        }
      }
      __syncthreads();
      {
        float yl = 0;
#pragma unroll
        for (int r = 0; r < 16; ++r) yl += sh_aux[r] * pW2[r];
        atomicAdd(&Y2p[(size_t)(fb&7)*HS + tid], yl);
      }
    }
    barrier_pf(bflags, brel, gen, [&]{ pfH1((s+1) & 3); }); ++gen;
  }

  // ---------- epilogue: final update (t=127, i=3) + output assembly ----------
  if (bid == 0) {
    float xn, cn;
    do_update(3, xn, cn);
    out[127*HS + tid] = xn;
    out[TT*HS + 3*HS + tid] = xn;                 // h_T[3]
    out[TT*HS + LNUM*HS + 3*HS + tid] = cn;       // c_T[3]
    out[TT*HS + 0*HS + tid] = h0;
    out[TT*HS + 1*HS + tid] = h1;
    out[TT*HS + 2*HS + tid] = h2;
    out[TT*HS + LNUM*HS + 0*HS + tid] = c0;
    out[TT*HS + LNUM*HS + 1*HS + tid] = c1r;
    out[TT*HS + LNUM*HS + 2*HS + tid] = c2r;
  }
}

// ---------------- host launcher ----------------
extern "C" void kernel_launch(void* const* d_in, const int* in_sizes, int n_in,
                              void* d_out, int out_size, void* d_ws, size_t ws_size,
                              hipStream_t stream) {
  const float* x      = (const float*)d_in[0];
  const float* hist   = (const float*)d_in[1];
  const float* Wx     = (const float*)d_in[2];
  const float* bx     = (const float*)d_in[3];
  const float* Wh     = (const float*)d_in[4];
  const float* bh     = (const float*)d_in[5];
  const float* saWin  = (const float*)d_in[6];
  const float* saBin  = (const float*)d_in[7];
  const float* saWo   = (const float*)d_in[8];
  const float* saBo   = (const float*)d_in[9];
  const float* caWin  = (const float*)d_in[10];
  const float* caBin  = (const float*)d_in[11];
  const float* caWo   = (const float*)d_in[12];
  const float* caBo   = (const float*)d_in[13];
  const float* ffW1   = (const float*)d_in[14];
  const float* ffB1   = (const float*)d_in[15];
  const float* ffW2   = (const float*)d_in[16];
  const float* ffB2   = (const float*)d_in[17];
  const float* lnG    = (const float*)d_in[18];
  const float* lnB    = (const float*)d_in[19];
  float* ws  = (float*)d_ws;
  float* out = (float*)d_out;

  // zero mutable state / planes / slots / counters / barrier flags
  hipMemsetAsync((char*)d_ws + OFF_STATE*sizeof(float), 0,
                 (WS_TOTAL - OFF_STATE)*sizeof(float), stream);

  kv_gemm<<<dim3(MMEM/64, HS/64, LNUM), 256, 0, stream>>>(hist, caWin, caBin, ws + OFF_K, HS);
  kv_gemm<<<dim3(MMEM/64, HS/64, LNUM), 256, 0, stream>>>(hist, caWin, caBin, ws + OFF_V, 2*HS);
  wcomb_gemm<<<dim3(HS/64, HS/64, LNUM), 256, 0, stream>>>(saWo, saWin, ws + OFF_WCOMB);
  wgc_gemm<<<dim3(FFD/64, HS/64, LNUM), 256, 0, stream>>>(ffW1, lnG, caWo, ws + OFF_WGC);
  csa_kernel<<<(LNUM*HS)/4, 256, 0, stream>>>(saWo, saBin, saBo, ws + OFF_CSA);
  transpose_scale<<<dim3(HS/32, HS/32, LNUM), 256, 0, stream>>>(
      caWin, (size_t)(3*HS)*HS, HS, HS, lnG, (size_t)(3*HS), ws + OFF_WQT, (size_t)HS*HS);
  sqcbq_kernel<<<(LNUM*HS)/4, 256, 0, stream>>>(caWin, caBin, lnG, lnB, ws + OFF_SQ, ws + OFF_CBQ);
  transpose_scale<<<dim3(FFD/32, HS/32, LNUM), 256, 0, stream>>>(
      ffW2, (size_t)HS*FFD, HS, FFD, nullptr, 0, ws + OFF_W2T, (size_t)FFD*HS);
  ffvec_kernel<<<(LNUM*FFD)/4, 256, 0, stream>>>(ffW1, ffB1, caBo, lnG, lnB,
      ws + OFF_SU, ws + OFF_CF1, ws + OFF_CF2);

  seq_kernel<<<NB, NT, 0, stream>>>(x, Wx, bx, Wh, bh, caWo, caBo,
                                    ffW1, ffB2, lnG, lnB, ws, out);
}

// Round 5
// 14176.678 us; speedup vs baseline: 1.3064x; 1.3064x over previous
//
#include <hip/hip_runtime.h>

#define HS   512
#define LNUM 4
#define TT   128
#define MMEM 2048
#define FFD  2048
#define NB   256
#define NT   512
#define INV512 (1.0f/512.0f)
#define QSCALE 0.08838834764831845f  // 1/sqrt(128)

// ---------------- workspace layout (float offsets) ----------------
constexpr size_t OFF_K     = 0;                                   // L*M*HS
constexpr size_t OFF_V     = OFF_K     + (size_t)LNUM*MMEM*HS;
constexpr size_t OFF_WCOMB = OFF_V     + (size_t)LNUM*MMEM*HS;    // L*HS*HS
constexpr size_t OFF_WQT   = OFF_WCOMB + (size_t)LNUM*HS*HS;      // L*HS*HS
constexpr size_t OFF_W2T   = OFF_WQT   + (size_t)LNUM*HS*HS;      // L*FF*HS
constexpr size_t OFF_CSA   = OFF_W2T   + (size_t)LNUM*FFD*HS;     // L*HS
constexpr size_t OFF_SQ    = OFF_CSA   + (size_t)LNUM*HS;         // L*HS
constexpr size_t OFF_CBQ   = OFF_SQ    + (size_t)LNUM*HS;         // L*HS
// mutable state (memset to 0)
constexpr size_t OFF_STATE = OFF_CBQ   + (size_t)LNUM*HS;
constexpr size_t OFF_H     = OFF_STATE;                           // 2*L*HS
constexpr size_t OFF_C     = OFF_H     + 2*LNUM*HS;               // 2*L*HS
constexpr size_t OFF_XING  = OFF_C     + 2*LNUM*HS;               // HS
constexpr size_t OFF_Z1    = OFF_XING  + HS;                      // HS
constexpr size_t OFF_Z02   = OFF_Z1    + HS;                      // 2*HS
constexpr size_t OFF_T2G   = OFF_Z02   + 2*HS;                    // HS
constexpr size_t OFF_YP    = OFF_T2G   + HS;                      // 4*HS planes
constexpr size_t OFF_Y2P   = OFF_YP    + 4*HS;                    // 8*HS planes
constexpr size_t OFF_CTXP  = OFF_Y2P   + 8*HS;                    // 8*HS planes
constexpr size_t OFF_DENS  = OFF_CTXP  + 8*HS;                    // 128 slots
constexpr size_t OFF_S1S   = OFF_DENS  + 128;                     // 32*2 slots
constexpr size_t OFF_S2S   = OFF_S1S   + 64;                      // 32*2 slots
constexpr size_t OFF_J1    = OFF_S2S   + 64;                      // 65*32 u32
constexpr size_t OFF_J2    = OFF_J1    + 65*32;                   // 128*32 u32
constexpr size_t OFF_FLAGS = OFF_J2    + 128*32;                  // NB*32 u32
constexpr size_t OFF_REL   = OFF_FLAGS + (size_t)NB*32;           // 32*32 u32
constexpr size_t WS_TOTAL  = OFF_REL   + 32*32;

__device__ __forceinline__ float wred(float v) {
#pragma unroll
  for (int m = 32; m; m >>= 1) v += __shfl_xor(v, m);
  return v;
}
__device__ __forceinline__ float sigm(float x) { return 1.0f/(1.0f+__expf(-x)); }

__device__ __forceinline__ float ald(const float* p) {
  return __hip_atomic_load(p, __ATOMIC_RELAXED, __HIP_MEMORY_SCOPE_AGENT);
}
__device__ __forceinline__ void ast(float* p, float v) {
  __hip_atomic_store(p, v, __ATOMIC_RELAXED, __HIP_MEMORY_SCOPE_AGENT);
}
__device__ __forceinline__ unsigned aldu(const unsigned* p) {
  return __hip_atomic_load(p, __ATOMIC_RELAXED, __HIP_MEMORY_SCOPE_AGENT);
}
__device__ __forceinline__ void astu(unsigned* p, unsigned v) {
  __hip_atomic_store(p, v, __ATOMIC_RELAXED, __HIP_MEMORY_SCOPE_AGENT);
}

// grid barrier: per-block arrival flags, block0 detects, REPLICATED release lines
template <class F>
__device__ __forceinline__ void barrier_pf(unsigned* flags, unsigned* rel,
                                           unsigned g, F&& pf) {
  asm volatile("s_waitcnt vmcnt(0)" ::: "memory");
  __syncthreads();
  const int tid = threadIdx.x;
  if (blockIdx.x == 0) {
    pf();
    if (tid >= 1 && tid < NB) {
      unsigned* f = flags + (size_t)tid*32;
      while (aldu(f) != g) __builtin_amdgcn_s_sleep(1);
    }
    __syncthreads();
    if (tid < 32) astu(rel + (size_t)tid*32, g);
    __syncthreads();
  } else {
    if (tid == 0) astu(flags + (size_t)blockIdx.x*32, g);
    pf();
    if (tid == 0) {
      const unsigned* r = rel + (size_t)(blockIdx.x & 31)*32;
      while (aldu(r) != g) __builtin_amdgcn_s_sleep(1);
    }
    __syncthreads();
  }
}

// narrow join: producer sets own flag (after draining stores)
__device__ __forceinline__ void jflag(unsigned* J, int id, unsigned val) {
  asm volatile("s_waitcnt vmcnt(0)" ::: "memory");
  __syncthreads();
  if (threadIdx.x == 0) astu(J + (size_t)id*32, val);
}
// consumer: threads [0,n) poll per-producer flags; pf overlaps the wait
template <class F>
__device__ __forceinline__ void jwait_pf(unsigned* J, int n, unsigned val, F&& pf) {
  pf();
  if (threadIdx.x < n) {
    const unsigned* f = J + (size_t)threadIdx.x*32;
    while ((int)(aldu(f) - val) < 0) __builtin_amdgcn_s_sleep(1);
  }
  __syncthreads();
}

// warp0: reduce 32 (sum,sumsq) slot pairs -> sh[o], sh[o+1]
__device__ __forceinline__ void slotred32(const float* slots, float* sh, int o,
                                          int w, int lane) {
  if (w == 0) {
    float a = (lane < 32) ? ald(slots + lane*2) : ald(slots + (lane-32)*2 + 1);
#pragma unroll
    for (int m = 16; m; m >>= 1) a += __shfl_xor(a, m);
    if (lane == 0)  sh[o]   = a;
    if (lane == 32) sh[o+1] = a;
  }
}

// ---------------- precompute kernels ----------------

__global__ __launch_bounds__(256) void kv_gemm(
    const float* __restrict__ hist, const float* __restrict__ caWin,
    const float* __restrict__ caBin, float* __restrict__ out, int koff) {
  __shared__ float As[16][64];
  __shared__ float Bs[16][64];
  const int l = blockIdx.z, m0 = blockIdx.x*64, f0 = blockIdx.y*64;
  const int tid = threadIdx.x, tm = tid >> 4, tf = tid & 15;
  float acc[4][4] = {};
  for (int e0 = 0; e0 < HS; e0 += 16) {
#pragma unroll
    for (int it = 0; it < 4; ++it) {
      int idx = tid + it*256, k = idx & 15, mm = idx >> 4;
      As[k][mm] = hist[((size_t)(m0+mm)*LNUM + l)*HS + e0 + k];
      Bs[k][mm] = caWin[((size_t)l*(3*HS) + koff + f0 + mm)*HS + e0 + k];
    }
    __syncthreads();
#pragma unroll
    for (int k = 0; k < 16; ++k) {
      float a[4], b[4];
#pragma unroll
      for (int x = 0; x < 4; ++x) { a[x] = As[k][tm*4+x]; b[x] = Bs[k][tf*4+x]; }
#pragma unroll
      for (int x = 0; x < 4; ++x)
#pragma unroll
        for (int y = 0; y < 4; ++y) acc[x][y] += a[x]*b[y];
    }
    __syncthreads();
  }
#pragma unroll
  for (int x = 0; x < 4; ++x)
#pragma unroll
    for (int y = 0; y < 4; ++y) {
      int m = m0 + tm*4 + x, f = f0 + tf*4 + y;
      out[((size_t)l*MMEM + m)*HS + f] = acc[x][y] + caBin[l*(3*HS) + koff + f];
    }
}

__global__ __launch_bounds__(256) void wcomb_gemm(
    const float* __restrict__ saWo, const float* __restrict__ saWin, float* __restrict__ wcomb) {
  __shared__ float As[16][64];
  __shared__ float Bs[16][64];
  const int l = blockIdx.z, f0 = blockIdx.x*64, j0 = blockIdx.y*64;
  const int tid = threadIdx.x, tm = tid >> 4, tf = tid & 15;
  float acc[4][4] = {};
  for (int e0 = 0; e0 < HS; e0 += 16) {
#pragma unroll
    for (int it = 0; it < 4; ++it) {
      int idx = tid + it*256;
      { int k = idx & 15, ff = idx >> 4;
        As[k][ff] = saWo[((size_t)l*HS + f0+ff)*HS + e0 + k]; }
      { int jj = idx & 63, k = idx >> 6;
        Bs[k][jj] = saWin[((size_t)l*(3*HS) + 2*HS + e0 + k)*HS + j0 + jj]; }
    }
    __syncthreads();
#pragma unroll
    for (int k = 0; k < 16; ++k) {
      float a[4], b[4];
#pragma unroll
      for (int x = 0; x < 4; ++x) { a[x] = As[k][tm*4+x]; b[x] = Bs[k][tf*4+x]; }
#pragma unroll
      for (int x = 0; x < 4; ++x)
#pragma unroll
        for (int y = 0; y < 4; ++y) acc[x][y] += a[x]*b[y];
    }
    __syncthreads();
  }
#pragma unroll
  for (int x = 0; x < 4; ++x)
#pragma unroll
    for (int y = 0; y < 4; ++y)
      wcomb[(size_t)l*HS*HS + (size_t)(f0+tm*4+x)*HS + (j0+tf*4+y)] = acc[x][y];
}

__global__ __launch_bounds__(256) void transpose_scale(
    const float* __restrict__ in, size_t inLS, int R, int C,
    const float* __restrict__ g, size_t gLS, float* __restrict__ out, size_t outLS) {
  __shared__ float tile[32][33];
  const int l = blockIdx.z, e0 = blockIdx.x*32, f0 = blockIdx.y*32;
  const int tx = threadIdx.x & 31, ty = threadIdx.x >> 5;
#pragma unroll
  for (int r = 0; r < 32; r += 8)
    tile[ty+r][tx] = in[(size_t)l*inLS + (size_t)(f0+ty+r)*C + e0 + tx];
  __syncthreads();
#pragma unroll
  for (int r = 0; r < 32; r += 8) {
    int e = e0 + ty + r, f = f0 + tx;
    float s = g ? g[(size_t)l*gLS + e] : 1.0f;
    out[(size_t)l*outLS + (size_t)e*R + f] = tile[tx][ty+r] * s;
  }
}

__global__ __launch_bounds__(256) void csa_kernel(
    const float* __restrict__ saWo, const float* __restrict__ sabin,
    const float* __restrict__ sabo, float* __restrict__ csa) {
  const int w = threadIdx.x >> 6, lane = threadIdx.x & 63;
  const int row = blockIdx.x*4 + w;
  const int l = row >> 9, f = row & 511;
  float acc = 0;
#pragma unroll
  for (int k = 0; k < 8; ++k) {
    int e = lane + 64*k;
    acc += saWo[((size_t)l*HS + f)*HS + e] * sabin[l*(3*HS) + 2*HS + e];
  }
  acc = wred(acc);
  if (lane == 0) csa[row] = acc + sabo[l*HS + f];
}

__global__ __launch_bounds__(256) void sqcbq_kernel(
    const float* __restrict__ caWin, const float* __restrict__ caBin,
    const float* __restrict__ lnG, const float* __restrict__ lnB,
    float* __restrict__ sq, float* __restrict__ cbq) {
  const int w = threadIdx.x >> 6, lane = threadIdx.x & 63;
  const int row = blockIdx.x*4 + w;
  const int l = row >> 9, f = row & 511;
  float a1 = 0, a2 = 0;
#pragma unroll
  for (int k = 0; k < 8; ++k) {
    int e = lane + 64*k;
    float wv = caWin[((size_t)l*(3*HS) + f)*HS + e];
    a1 += wv * lnG[l*(3*HS) + e];
    a2 += wv * lnB[l*(3*HS) + e];
  }
  a1 = wred(a1); a2 = wred(a2);
  if (lane == 0) { sq[row] = a1; cbq[row] = a2 + caBin[l*(3*HS) + f]; }
}

// ---------------- main persistent sequential kernel ----------------

__global__ __launch_bounds__(NT, 2) void seq_kernel(
    const float* __restrict__ x,
    const float* __restrict__ Wx,  const float* __restrict__ bx,
    const float* __restrict__ Wh,  const float* __restrict__ bh,
    const float* __restrict__ caWo, const float* __restrict__ caBo,
    const float* __restrict__ ffW1, const float* __restrict__ ffB1,
    const float* __restrict__ ffB2,
    const float* __restrict__ lnG,  const float* __restrict__ lnB,
    float* __restrict__ ws, float* __restrict__ out) {
  const float* Kb    = ws + OFF_K;
  const float* Vb    = ws + OFF_V;
  const float* Wcomb = ws + OFF_WCOMB;
  const float* WqT   = ws + OFF_WQT;
  const float* W2T   = ws + OFF_W2T;
  const float* csag  = ws + OFF_CSA;
  const float* sqg   = ws + OFF_SQ;
  const float* cbqg  = ws + OFF_CBQ;
  float* hG    = ws + OFF_H;
  float* cG    = ws + OFF_C;
  float* xing  = ws + OFF_XING;
  float* z1g   = ws + OFF_Z1;
  float* z02g  = ws + OFF_Z02;
  float* t2g   = ws + OFF_T2G;
  float* Yp    = ws + OFF_YP;
  float* Y2p   = ws + OFF_Y2P;
  float* ctxP  = ws + OFF_CTXP;
  float* denS  = ws + OFF_DENS;
  float* s1s   = ws + OFF_S1S;
  float* s2s   = ws + OFF_S2S;
  unsigned* J1     = (unsigned*)(ws + OFF_J1);
  unsigned* J2     = (unsigned*)(ws + OFF_J2);
  unsigned* bflags = (unsigned*)(ws + OFF_FLAGS);
  unsigned* brel   = (unsigned*)(ws + OFF_REL);

  __shared__ float sh_xin[HS], sh_h[HS], sh_vec[HS], sh_aux[HS];
  __shared__ float sh_q[128], sh_p[64], sh_t1[16];
  __shared__ float sh_red[24], sh_den[4];

  const int bid = blockIdx.x, tid = threadIdx.x;
  const int w = tid >> 6, lane = tid & 63;
  unsigned gen = 1;

  // prefetch register files
  float pZx[8], pZh[8];      // H1 z1 rows (bid<64)
  float pZx2[8], pZh2[8];    // H3-window z0/z2 rows (bid<32 | bid>=160)
  float pWc[2][8], pWq[16];  // H2 (bid<32)
  float pK[8][2], pV[16];    // H3 attn (32<=bid<160)
  float pCa[2][8];           // H4 (bid<32)
  float pF1[8], pW2[8];      // H5 (all)

  auto pfH1 = [&](int l) {
    if (bid < 64) {
      const float* wxr = Wx + (((size_t)l*3 + 1)*HS + bid*8 + w)*HS;
      const float* whr = Wh + (((size_t)l*3 + 1)*HS + bid*8 + w)*HS;
#pragma unroll
      for (int k = 0; k < 8; ++k) { pZx[k] = wxr[lane+64*k]; pZh[k] = whr[lane+64*k]; }
    }
  };
  auto pfH2 = [&](int l) {
#pragma unroll
    for (int rr = 0; rr < 2; ++rr) {
      const float* wr = Wcomb + ((size_t)l*HS + bid*16 + w*2 + rr)*HS;
#pragma unroll
      for (int k = 0; k < 8; ++k) pWc[rr][k] = wr[lane+64*k];
    }
#pragma unroll
    for (int r = 0; r < 16; ++r)
      pWq[r] = WqT[((size_t)l*HS + bid*16 + r)*HS + tid];
  };
  auto pfH3 = [&](int l) {
    if (bid >= 32 && bid < 160) {
      const int b2 = bid - 32, h = b2 >> 5, mseg = b2 & 31;
#pragma unroll
      for (int rr = 0; rr < 8; ++rr) {
        const float* kr = Kb + ((size_t)l*MMEM + mseg*64 + w*8 + rr)*HS + h*128;
        pK[rr][0] = kr[lane]; pK[rr][1] = kr[lane+64];
      }
#pragma unroll
      for (int ml = 0; ml < 16; ++ml)
        pV[ml] = Vb[((size_t)l*MMEM + mseg*64 + (tid>>7)*16 + ml)*HS + h*128 + (tid & 127)];
    } else {
      const int zb = (bid < 32) ? bid : bid - 128;
      const int rowid = zb*8 + w;
      const int g = (rowid < 512) ? 0 : 2;
      const int f = rowid & 511;
      const float* wxr = Wx + (((size_t)l*3 + g)*HS + f)*HS;
      const float* whr = Wh + (((size_t)l*3 + g)*HS + f)*HS;
#pragma unroll
      for (int k = 0; k < 8; ++k) { pZx2[k] = wxr[lane+64*k]; pZh2[k] = whr[lane+64*k]; }
    }
  };
  auto pfH4 = [&](int l) {
#pragma unroll
    for (int rr = 0; rr < 2; ++rr) {
      const float* wr = caWo + ((size_t)l*HS + bid*16 + w*2 + rr)*HS;
#pragma unroll
      for (int k = 0; k < 8; ++k) pCa[rr][k] = wr[lane+64*k];
    }
  };
  auto pfH5 = [&](int l) {
    const float* wr = ffW1 + ((size_t)l*FFD + bid*8 + w)*HS;
#pragma unroll
    for (int k = 0; k < 8; ++k) pF1[k] = wr[lane+64*k];
#pragma unroll
    for (int r = 0; r < 8; ++r)
      pW2[r] = W2T[((size_t)l*FFD + bid*8 + r)*HS + tid];
  };

  // fused LSTM update for step s-1; executed by blocks < 64 only
  auto do_update = [&](int ip, int parp, float& xn, float& cn) {
    const int j = tid;
    float t2v = ald(t2g + j);
    float z0  = ald(z02g + j);
    float z2  = ald(z02g + HS + j);
    float y2 = 0;
#pragma unroll
    for (int p = 0; p < 8; ++p) y2 += ald(Y2p + (size_t)p*HS + j);
    slotred32(s2s, sh_red, 16, w, lane);
    __syncthreads();
    float m2 = sh_red[16]*INV512;
    float r2 = rsqrtf(sh_red[17]*INV512 - m2*m2 + 1e-5f);
    float x2 = (t2v-m2)*r2*lnG[(ip*3+1)*HS+j] + lnB[(ip*3+1)*HS+j];
    float t3 = x2 + y2 + ffB2[ip*HS + j];
    float s_ = t3, q_ = t3*t3;
#pragma unroll
    for (int m = 32; m; m >>= 1) { s_ += __shfl_xor(s_, m); q_ += __shfl_xor(q_, m); }
    if (lane == 0) { sh_red[w] = s_; sh_red[8+w] = q_; }
    __syncthreads();
    if (tid == 0) {
      float a = 0, b = 0;
#pragma unroll
      for (int k = 0; k < 8; ++k) { a += sh_red[k]; b += sh_red[8+k]; }
      sh_red[0] = a; sh_red[1] = b;
    }
    __syncthreads();
    float m3 = sh_red[0]*INV512;
    float r3 = rsqrtf(sh_red[1]*INV512 - m3*m3 + 1e-5f);
    float d  = (t3-m3)*r3*lnG[(ip*3+2)*HS+j] + lnB[(ip*3+2)*HS+j];
    float cp = ald(cG + (parp*LNUM + ip)*HS + j);
    float ft = sigm(cp - d);
    float it = sigm(z0);
    float gt = tanhf(z2);
    cn = ft*cp + it*gt;
    xn = tanhf(cn);
  };

  pfH1(0);

  for (int s = 0; s < TT*LNUM; ++s) {
    const int t = s >> 2, i = s & 3;
    const int par = t & 1;
    const unsigned jv = (unsigned)(s + 1);
    // ---------- H1 window: update(s-1) + z1 matvec (0-63); zeroers (64-66) ----------
    if (bid < 64) {
      float xn = 0.f, cn = 0.f;
      if (s > 0) {
        const int ip = (s-1) & 3, tp = (s-1) >> 2, parp = tp & 1;
        if (bid == 0 || i > 0) {
          do_update(ip, parp, xn, cn);
          if (bid == 0) {
            ast(hG + ((parp^1)*LNUM + ip)*HS + tid, xn);
            ast(cG + ((parp^1)*LNUM + ip)*HS + tid, cn);
            if (ip == 3) out[tp*HS + tid] = xn;
          }
        }
      }
      float xv = (i == 0) ? x[t*HS + tid] : xn;
      sh_xin[tid] = xv;
      sh_h[tid]   = ald(hG + (par*LNUM + i)*HS + tid);
      if (bid == 0) ast(xing + tid, xv);
      __syncthreads();
      const int f = bid*8 + w;
      float acc = 0;
#pragma unroll
      for (int k = 0; k < 8; ++k) {
        int e = lane + 64*k;
        acc += pZx[k]*sh_xin[e] + pZh[k]*sh_h[e];
      }
      acc = wred(acc);
      if (lane == 0) ast(z1g + f, acc + bx[(i*3+1)*HS + f] + bh[(i*3+1)*HS + f]);
      jflag(J1, bid, jv);
    } else if (bid == 64) {
#pragma unroll
      for (int p = 0; p < 4; ++p) ast(Yp + (size_t)p*HS + tid, 0.f);
      jflag(J1, 64, jv);
    } else if (bid == 65) {
#pragma unroll
      for (int p = 0; p < 8; ++p) ast(ctxP + (size_t)p*HS + tid, 0.f);
    } else if (bid == 66) {
      jwait_pf(J1, 65, jv, [&]{});
#pragma unroll
      for (int p = 0; p < 8; ++p) ast(Y2p + (size_t)p*HS + tid, 0.f);
    }
    // ---------- J1 -> H2 (blocks 0-31): t1 + deferred q + stats1 slots ----------
    if (bid < 32) {
      jwait_pf(J1, 65, jv, [&]{ pfH2(i); });
      sh_vec[tid] = sigm(ald(z1g + tid));  // f0
      __syncthreads();
#pragma unroll
      for (int rr = 0; rr < 2; ++rr) {
        const int r = w*2 + rr, j = bid*16 + r;
        float acc = 0;
#pragma unroll
        for (int k = 0; k < 8; ++k) acc += pWc[rr][k]*sh_vec[lane + 64*k];
        acc = wred(acc);
        if (lane == 0) {
          float t1v = sh_vec[j] + acc + csag[i*HS + j];
          sh_t1[r]  = t1v;
          sh_aux[r] = t1v;
        }
      }
      __syncthreads();
      {
        float yl = 0;
#pragma unroll
        for (int r = 0; r < 16; ++r) yl += sh_aux[r] * pWq[r];
        atomicAdd(&Yp[(size_t)(bid & 3)*HS + tid], yl);
      }
      if (w == 0 && lane < 16) {
        float v = sh_aux[lane], s_ = v, q_ = v*v;
#pragma unroll
        for (int m = 8; m; m >>= 1) { s_ += __shfl_xor(s_, m); q_ += __shfl_xor(q_, m); }
        if (lane == 0) { ast(s1s + bid*2, s_); ast(s1s + bid*2 + 1, q_); }
      }
    }
    barrier_pf(bflags, brel, gen, [&]{ pfH3(i); });
    // ---------- H3 window: attention (32-159) | z0/z2 (0-31, 160-255) ----------
    if (bid >= 32 && bid < 160) {
      const int b2 = bid - 32, h = b2 >> 5, mseg = b2 & 31;
      slotred32(s1s, sh_red, 18, w, lane);
      __syncthreads();
      if (tid < 128) {
        float m1 = sh_red[18]*INV512;
        float r1 = rsqrtf(sh_red[19]*INV512 - m1*m1 + 1e-5f);
        int f = h*128 + tid;
        float Ysum = 0;
#pragma unroll
        for (int p = 0; p < 4; ++p) Ysum += ald(Yp + (size_t)p*HS + f);
        sh_q[tid] = r1*(Ysum - m1*sqg[i*HS + f]) + cbqg[i*HS + f];
      }
      __syncthreads();
#pragma unroll
      for (int rr = 0; rr < 8; ++rr) {
        float acc = sh_q[lane]*pK[rr][0] + sh_q[lane+64]*pK[rr][1];
        acc = wred(acc);
        if (lane == 0) sh_p[w*8 + rr] = __expf(acc * QSCALE);
      }
      __syncthreads();
      {
        const int d = tid & 127, mg = tid >> 7;
        float acc = 0;
#pragma unroll
        for (int ml = 0; ml < 16; ++ml) acc += sh_p[mg*16 + ml] * pV[ml];
        atomicAdd(&ctxP[(size_t)((b2 & 1)*4 + mg)*HS + h*128 + d], acc);
      }
      if (w == 0) {
        float v = wred(sh_p[lane]);
        if (lane == 0) ast(denS + h*32 + mseg, v);
      }
      jflag(J2, b2, jv);
    } else {
      const int zb = (bid < 32) ? bid : bid - 128;
      if (bid >= 160) {
        sh_xin[tid] = ald(xing + tid);
        sh_h[tid]   = ald(hG + (par*LNUM + i)*HS + tid);
      }
      __syncthreads();
      const int rowid = zb*8 + w;
      const int g = (rowid < 512) ? 0 : 2;
      const int f = rowid & 511;
      float acc = 0;
#pragma unroll
      for (int k = 0; k < 8; ++k) {
        int e = lane + 64*k;
        acc += pZx2[k]*sh_xin[e] + pZh2[k]*sh_h[e];
      }
      acc = wred(acc);
      if (lane == 0) ast(z02g + (g ? HS : 0) + f, acc + bx[(i*3+g)*HS + f] + bh[(i*3+g)*HS + f]);
      // ---------- J2 -> H4 (blocks 0-31): t2 + stats2 slots ----------
      if (bid < 32) {
        jwait_pf(J2, 128, jv, [&]{ pfH4(i); });
        slotred32(s1s, sh_red, 18, w, lane);
        if (w >= 4) {
          float v = (lane < 32) ? ald(denS + (w-4)*32 + lane) : 0.f;
#pragma unroll
          for (int m = 16; m; m >>= 1) v += __shfl_xor(v, m);
          if (lane == 0) sh_den[w-4] = v;
        }
        __syncthreads();
        const float m1 = sh_red[18]*INV512;
        const float r1 = rsqrtf(sh_red[19]*INV512 - m1*m1 + 1e-5f);
        {
          float c = 0;
#pragma unroll
          for (int p = 0; p < 8; ++p) c += ald(ctxP + (size_t)p*HS + tid);
          sh_vec[tid] = c / sh_den[tid >> 7];
        }
        __syncthreads();
#pragma unroll
        for (int rr = 0; rr < 2; ++rr) {
          const int r = w*2 + rr, j = bid*16 + r;
          float a2 = 0;
#pragma unroll
          for (int k = 0; k < 8; ++k) a2 += pCa[rr][k]*sh_vec[lane + 64*k];
          a2 = wred(a2);
          if (lane == 0) {
            float x1 = (sh_t1[r]-m1)*r1*lnG[(i*3)*HS + j] + lnB[(i*3)*HS + j];
            float t2v = x1 + a2 + caBo[i*HS + j];
            ast(t2g + j, t2v);
            sh_aux[r] = t2v;
          }
        }
        __syncthreads();
        if (w == 0 && lane < 16) {
          float v = sh_aux[lane], s_ = v, q_ = v*v;
#pragma unroll
          for (int m = 8; m; m >>= 1) { s_ += __shfl_xor(s_, m); q_ += __shfl_xor(q_, m); }
          if (lane == 0) { ast(s2s + bid*2, s_); ast(s2s + bid*2 + 1, q_); }
        }
      }
    }
    barrier_pf(bflags, brel, gen+1, [&]{ pfH5(i); });
    // ---------- H5: all blocks: ff1 = relu(W1@x2+b1); Y2 plane += W2T@ff1 ----------
    {
      slotred32(s2s, sh_red, 16, w, lane);
      __syncthreads();
      const float m2 = sh_red[16]*INV512;
      const float r2 = rsqrtf(sh_red[17]*INV512 - m2*m2 + 1e-5f);
      sh_vec[tid] = (ald(t2g + tid)-m2)*r2*lnG[(i*3+1)*HS + tid] + lnB[(i*3+1)*HS + tid];
      __syncthreads();
      const int kk = bid*8 + w;
      float acc = 0;
#pragma unroll
      for (int k = 0; k < 8; ++k) acc += pF1[k]*sh_vec[lane + 64*k];
      acc = wred(acc);
      if (lane == 0) sh_aux[w] = fmaxf(acc + ffB1[i*FFD + kk], 0.f);
      __syncthreads();
      float yl = 0;
#pragma unroll
      for (int r = 0; r < 8; ++r) yl += sh_aux[r] * pW2[r];
      atomicAdd(&Y2p[(size_t)(bid & 7)*HS + tid], yl);
    }
    barrier_pf(bflags, brel, gen+2, [&]{ pfH1((s+1) & 3); });
    gen += 3;
  }

  // ---------- epilogue: final update (t=127, i=3) + output assembly ----------
  if (bid == 0) {
    float xn, cn;
    do_update(3, 1, xn, cn);
    out[127*HS + tid] = xn;
    out[TT*HS + 3*HS + tid] = xn;                 // h_T[3]
    out[TT*HS + LNUM*HS + 3*HS + tid] = cn;       // c_T[3]
#pragma unroll
    for (int ii = 0; ii < 3; ++ii) {
      out[TT*HS + ii*HS + tid]            = ald(hG + (0*LNUM + ii)*HS + tid);
      out[TT*HS + LNUM*HS + ii*HS + tid]  = ald(cG + (0*LNUM + ii)*HS + tid);
    }
  }
}

// ---------------- host launcher ----------------
extern "C" void kernel_launch(void* const* d_in, const int* in_sizes, int n_in,
                              void* d_out, int out_size, void* d_ws, size_t ws_size,
                              hipStream_t stream) {
  const float* x      = (const float*)d_in[0];
  const float* hist   = (const float*)d_in[1];
  const float* Wx     = (const float*)d_in[2];
  const float* bx     = (const float*)d_in[3];
  const float* Wh     = (const float*)d_in[4];
  const float* bh     = (const float*)d_in[5];
  const float* saWin  = (const float*)d_in[6];
  const float* saBin  = (const float*)d_in[7];
  const float* saWo   = (const float*)d_in[8];
  const float* saBo   = (const float*)d_in[9];
  const float* caWin  = (const float*)d_in[10];
  const float* caBin  = (const float*)d_in[11];
  const float* caWo   = (const float*)d_in[12];
  const float* caBo   = (const float*)d_in[13];
  const float* ffW1   = (const float*)d_in[14];
  const float* ffB1   = (const float*)d_in[15];
  const float* ffW2   = (const float*)d_in[16];
  const float* ffB2   = (const float*)d_in[17];
  const float* lnG    = (const float*)d_in[18];
  const float* lnB    = (const float*)d_in[19];
  float* ws  = (float*)d_ws;
  float* out = (float*)d_out;

  hipMemsetAsync((char*)d_ws + OFF_STATE*sizeof(float), 0,
                 (WS_TOTAL - OFF_STATE)*sizeof(float), stream);

  kv_gemm<<<dim3(MMEM/64, HS/64, LNUM), 256, 0, stream>>>(hist, caWin, caBin, ws + OFF_K, HS);
  kv_gemm<<<dim3(MMEM/64, HS/64, LNUM), 256, 0, stream>>>(hist, caWin, caBin, ws + OFF_V, 2*HS);
  wcomb_gemm<<<dim3(HS/64, HS/64, LNUM), 256, 0, stream>>>(saWo, saWin, ws + OFF_WCOMB);
  csa_kernel<<<(LNUM*HS)/4, 256, 0, stream>>>(saWo, saBin, saBo, ws + OFF_CSA);
  transpose_scale<<<dim3(HS/32, HS/32, LNUM), 256, 0, stream>>>(
      caWin, (size_t)(3*HS)*HS, HS, HS, lnG, (size_t)(3*HS), ws + OFF_WQT, (size_t)HS*HS);
  sqcbq_kernel<<<(LNUM*HS)/4, 256, 0, stream>>>(caWin, caBin, lnG, lnB, ws + OFF_SQ, ws + OFF_CBQ);
  transpose_scale<<<dim3(FFD/32, HS/32, LNUM), 256, 0, stream>>>(
      ffW2, (size_t)HS*FFD, HS, FFD, nullptr, 0, ws + OFF_W2T, (size_t)FFD*HS);

  seq_kernel<<<NB, NT, 0, stream>>>(x, Wx, bx, Wh, bh, caWo, caBo,
                                    ffW1, ffB1, ffB2, lnG, lnB, ws, out);
}

// Round 6
// 13823.012 us; speedup vs baseline: 1.3398x; 1.0256x over previous
//
#include <hip/hip_runtime.h>

#define HS   512
#define LNUM 4
#define TT   128
#define MMEM 2048
#define FFD  2048
#define NB   256
#define NT   512
#define INV512 (1.0f/512.0f)
#define QSCALE 0.08838834764831845f  // 1/sqrt(128)

// ---------------- workspace layout (float offsets; bf16 arrays take half) ----
constexpr size_t KHALF = (size_t)LNUM*MMEM*HS/2;
constexpr size_t HHALF = (size_t)LNUM*HS*HS/2;
constexpr size_t FHALF = (size_t)LNUM*FFD*HS/2;
constexpr size_t OFF_KBF    = 0;
constexpr size_t OFF_VBF    = OFF_KBF    + KHALF;
constexpr size_t OFF_WCOMBBF= OFF_VBF    + KHALF;
constexpr size_t OFF_WQTBF  = OFF_WCOMBBF+ HHALF;
constexpr size_t OFF_W2TBF  = OFF_WQTBF  + HHALF;
constexpr size_t OFF_FFW1BF = OFF_W2TBF  + FHALF;
constexpr size_t OFF_CAWOBF = OFF_FFW1BF + FHALF;
constexpr size_t OFF_CSA    = OFF_CAWOBF + HHALF;                 // L*HS
constexpr size_t OFF_SQ     = OFF_CSA    + (size_t)LNUM*HS;       // L*HS
constexpr size_t OFF_CBQ    = OFF_SQ     + (size_t)LNUM*HS;       // L*HS
// mutable state (memset to 0)
constexpr size_t OFF_STATE = OFF_CBQ   + (size_t)LNUM*HS;
constexpr size_t OFF_H     = OFF_STATE;                           // 2*L*HS
constexpr size_t OFF_C     = OFF_H     + 2*LNUM*HS;               // 2*L*HS
constexpr size_t OFF_XING  = OFF_C     + 2*LNUM*HS;               // HS
constexpr size_t OFF_Z1    = OFF_XING  + HS;                      // HS
constexpr size_t OFF_Z02   = OFF_Z1    + HS;                      // 2*HS
constexpr size_t OFF_T2G   = OFF_Z02   + 2*HS;                    // HS
constexpr size_t OFF_YP    = OFF_T2G   + HS;                      // 4*HS planes
constexpr size_t OFF_Y2P   = OFF_YP    + 4*HS;                    // 8*HS planes
constexpr size_t OFF_CTXP  = OFF_Y2P   + 8*HS;                    // 8*HS planes
constexpr size_t OFF_DENS  = OFF_CTXP  + 8*HS;                    // 128 slots
constexpr size_t OFF_S1S   = OFF_DENS  + 128;                     // 32*2 slots
constexpr size_t OFF_S2S   = OFF_S1S   + 64;                      // 32*2 slots
constexpr size_t OFF_J1    = OFF_S2S   + 64;                      // 65*32 u32
constexpr size_t OFF_J2    = OFF_J1    + 65*32;                   // 128*32 u32
constexpr size_t OFF_FLAGS = OFF_J2    + 128*32;                  // NB*32 u32
constexpr size_t WS_TOTAL  = OFF_FLAGS + (size_t)NB*32;

__device__ __forceinline__ float wred(float v) {
#pragma unroll
  for (int m = 32; m; m >>= 1) v += __shfl_xor(v, m);
  return v;
}
__device__ __forceinline__ float sigm(float x) { return 1.0f/(1.0f+__expf(-x)); }

__device__ __forceinline__ unsigned short f2bf(float f) {
  unsigned u = __float_as_uint(f);
  unsigned r = (u + 0x7fffu + ((u >> 16) & 1u)) >> 16;
  return (unsigned short)r;
}
__device__ __forceinline__ float bf2f(unsigned short h) {
  return __uint_as_float(((unsigned)h) << 16);
}

__device__ __forceinline__ float ald(const float* p) {
  return __hip_atomic_load(p, __ATOMIC_RELAXED, __HIP_MEMORY_SCOPE_AGENT);
}
__device__ __forceinline__ void ast(float* p, float v) {
  __hip_atomic_store(p, v, __ATOMIC_RELAXED, __HIP_MEMORY_SCOPE_AGENT);
}
__device__ __forceinline__ unsigned aldu(const unsigned* p) {
  return __hip_atomic_load(p, __ATOMIC_RELAXED, __HIP_MEMORY_SCOPE_AGENT);
}
__device__ __forceinline__ void astu(unsigned* p, unsigned v) {
  __hip_atomic_store(p, v, __ATOMIC_RELAXED, __HIP_MEMORY_SCOPE_AGENT);
}

// direct-poll grid barrier: set own flag, prefetch, poll ALL flags (monotonic)
template <class F>
__device__ __forceinline__ void barrier_pf(unsigned* flags, unsigned g, F&& pf) {
  asm volatile("s_waitcnt vmcnt(0)" ::: "memory");
  __syncthreads();
  if (threadIdx.x == 0) astu(flags + (size_t)blockIdx.x*32, g);
  pf();
  if (threadIdx.x < NB) {
    const unsigned* f = flags + (size_t)threadIdx.x*32;
    while ((int)(aldu(f) - g) < 0) __builtin_amdgcn_s_sleep(2);
  }
  __syncthreads();
}

// narrow join: producer sets own flag (after draining stores)
__device__ __forceinline__ void jflag(unsigned* J, int id, unsigned val) {
  asm volatile("s_waitcnt vmcnt(0)" ::: "memory");
  __syncthreads();
  if (threadIdx.x == 0) astu(J + (size_t)id*32, val);
}
template <class F>
__device__ __forceinline__ void jwait_pf(unsigned* J, int n, unsigned val, F&& pf) {
  pf();
  if (threadIdx.x < n) {
    const unsigned* f = J + (size_t)threadIdx.x*32;
    while ((int)(aldu(f) - val) < 0) __builtin_amdgcn_s_sleep(1);
  }
  __syncthreads();
}

// warp0: reduce 32 (sum,sumsq) slot pairs -> sh[o], sh[o+1]
__device__ __forceinline__ void slotred32(const float* slots, float* sh, int o,
                                          int w, int lane) {
  if (w == 0) {
    float a = (lane < 32) ? ald(slots + lane*2) : ald(slots + (lane-32)*2 + 1);
#pragma unroll
    for (int m = 16; m; m >>= 1) a += __shfl_xor(a, m);
    if (lane == 0)  sh[o]   = a;
    if (lane == 32) sh[o+1] = a;
  }
}

// ---------------- precompute kernels ----------------

__global__ __launch_bounds__(256) void kv_gemm(
    const float* __restrict__ hist, const float* __restrict__ caWin,
    const float* __restrict__ caBin, unsigned short* __restrict__ out, int koff) {
  __shared__ float As[16][64];
  __shared__ float Bs[16][64];
  const int l = blockIdx.z, m0 = blockIdx.x*64, f0 = blockIdx.y*64;
  const int tid = threadIdx.x, tm = tid >> 4, tf = tid & 15;
  float acc[4][4] = {};
  for (int e0 = 0; e0 < HS; e0 += 16) {
#pragma unroll
    for (int it = 0; it < 4; ++it) {
      int idx = tid + it*256, k = idx & 15, mm = idx >> 4;
      As[k][mm] = hist[((size_t)(m0+mm)*LNUM + l)*HS + e0 + k];
      Bs[k][mm] = caWin[((size_t)l*(3*HS) + koff + f0 + mm)*HS + e0 + k];
    }
    __syncthreads();
#pragma unroll
    for (int k = 0; k < 16; ++k) {
      float a[4], b[4];
#pragma unroll
      for (int x = 0; x < 4; ++x) { a[x] = As[k][tm*4+x]; b[x] = Bs[k][tf*4+x]; }
#pragma unroll
      for (int x = 0; x < 4; ++x)
#pragma unroll
        for (int y = 0; y < 4; ++y) acc[x][y] += a[x]*b[y];
    }
    __syncthreads();
  }
#pragma unroll
  for (int x = 0; x < 4; ++x)
#pragma unroll
    for (int y = 0; y < 4; ++y) {
      int m = m0 + tm*4 + x, f = f0 + tf*4 + y;
      out[((size_t)l*MMEM + m)*HS + f] = f2bf(acc[x][y] + caBin[l*(3*HS) + koff + f]);
    }
}

__global__ __launch_bounds__(256) void wcomb_gemm(
    const float* __restrict__ saWo, const float* __restrict__ saWin,
    unsigned short* __restrict__ wcomb) {
  __shared__ float As[16][64];
  __shared__ float Bs[16][64];
  const int l = blockIdx.z, f0 = blockIdx.x*64, j0 = blockIdx.y*64;
  const int tid = threadIdx.x, tm = tid >> 4, tf = tid & 15;
  float acc[4][4] = {};
  for (int e0 = 0; e0 < HS; e0 += 16) {
#pragma unroll
    for (int it = 0; it < 4; ++it) {
      int idx = tid + it*256;
      { int k = idx & 15, ff = idx >> 4;
        As[k][ff] = saWo[((size_t)l*HS + f0+ff)*HS + e0 + k]; }
      { int jj = idx & 63, k = idx >> 6;
        Bs[k][jj] = saWin[((size_t)l*(3*HS) + 2*HS + e0 + k)*HS + j0 + jj]; }
    }
    __syncthreads();
#pragma unroll
    for (int k = 0; k < 16; ++k) {
      float a[4], b[4];
#pragma unroll
      for (int x = 0; x < 4; ++x) { a[x] = As[k][tm*4+x]; b[x] = Bs[k][tf*4+x]; }
#pragma unroll
      for (int x = 0; x < 4; ++x)
#pragma unroll
        for (int y = 0; y < 4; ++y) acc[x][y] += a[x]*b[y];
    }
    __syncthreads();
  }
#pragma unroll
  for (int x = 0; x < 4; ++x)
#pragma unroll
    for (int y = 0; y < 4; ++y)
      wcomb[(size_t)l*HS*HS + (size_t)(f0+tm*4+x)*HS + (j0+tf*4+y)] = f2bf(acc[x][y]);
}

__global__ __launch_bounds__(256) void transpose_scale_bf(
    const float* __restrict__ in, size_t inLS, int R, int C,
    const float* __restrict__ g, size_t gLS,
    unsigned short* __restrict__ out, size_t outLS) {
  __shared__ float tile[32][33];
  const int l = blockIdx.z, e0 = blockIdx.x*32, f0 = blockIdx.y*32;
  const int tx = threadIdx.x & 31, ty = threadIdx.x >> 5;
#pragma unroll
  for (int r = 0; r < 32; r += 8)
    tile[ty+r][tx] = in[(size_t)l*inLS + (size_t)(f0+ty+r)*C + e0 + tx];
  __syncthreads();
#pragma unroll
  for (int r = 0; r < 32; r += 8) {
    int e = e0 + ty + r, f = f0 + tx;
    float s = g ? g[(size_t)l*gLS + e] : 1.0f;
    out[(size_t)l*outLS + (size_t)e*R + f] = f2bf(tile[tx][ty+r] * s);
  }
}

__global__ __launch_bounds__(256) void bf16_copy(
    const float* __restrict__ in, unsigned short* __restrict__ out, size_t n) {
  for (size_t i = (size_t)blockIdx.x*256 + threadIdx.x; i < n; i += (size_t)gridDim.x*256)
    out[i] = f2bf(in[i]);
}

__global__ __launch_bounds__(256) void csa_kernel(
    const float* __restrict__ saWo, const float* __restrict__ sabin,
    const float* __restrict__ sabo, float* __restrict__ csa) {
  const int w = threadIdx.x >> 6, lane = threadIdx.x & 63;
  const int row = blockIdx.x*4 + w;
  const int l = row >> 9, f = row & 511;
  float acc = 0;
#pragma unroll
  for (int k = 0; k < 8; ++k) {
    int e = lane + 64*k;
    acc += saWo[((size_t)l*HS + f)*HS + e] * sabin[l*(3*HS) + 2*HS + e];
  }
  acc = wred(acc);
  if (lane == 0) csa[row] = acc + sabo[l*HS + f];
}

__global__ __launch_bounds__(256) void sqcbq_kernel(
    const float* __restrict__ caWin, const float* __restrict__ caBin,
    const float* __restrict__ lnG, const float* __restrict__ lnB,
    float* __restrict__ sq, float* __restrict__ cbq) {
  const int w = threadIdx.x >> 6, lane = threadIdx.x & 63;
  const int row = blockIdx.x*4 + w;
  const int l = row >> 9, f = row & 511;
  float a1 = 0, a2 = 0;
#pragma unroll
  for (int k = 0; k < 8; ++k) {
    int e = lane + 64*k;
    float wv = caWin[((size_t)l*(3*HS) + f)*HS + e];
    a1 += wv * lnG[l*(3*HS) + e];
    a2 += wv * lnB[l*(3*HS) + e];
  }
  a1 = wred(a1); a2 = wred(a2);
  if (lane == 0) { sq[row] = a1; cbq[row] = a2 + caBin[l*(3*HS) + f]; }
}

// ---------------- main persistent sequential kernel ----------------

__global__ __launch_bounds__(NT, 2) void seq_kernel(
    const float* __restrict__ x,
    const float* __restrict__ Wx,  const float* __restrict__ bx,
    const float* __restrict__ Wh,  const float* __restrict__ bh,
    const float* __restrict__ caBo,
    const float* __restrict__ ffB1,
    const float* __restrict__ ffB2,
    const float* __restrict__ lnG,  const float* __restrict__ lnB,
    float* __restrict__ ws, float* __restrict__ out) {
  const unsigned short* Kb    = (const unsigned short*)(ws + OFF_KBF);
  const unsigned short* Vb    = (const unsigned short*)(ws + OFF_VBF);
  const unsigned short* Wcomb = (const unsigned short*)(ws + OFF_WCOMBBF);
  const unsigned short* WqT   = (const unsigned short*)(ws + OFF_WQTBF);
  const unsigned short* W2T   = (const unsigned short*)(ws + OFF_W2TBF);
  const unsigned short* F1b   = (const unsigned short*)(ws + OFF_FFW1BF);
  const unsigned short* CaWob = (const unsigned short*)(ws + OFF_CAWOBF);
  const float* csag  = ws + OFF_CSA;
  const float* sqg   = ws + OFF_SQ;
  const float* cbqg  = ws + OFF_CBQ;
  float* hG    = ws + OFF_H;
  float* cG    = ws + OFF_C;
  float* xing  = ws + OFF_XING;
  float* z1g   = ws + OFF_Z1;
  float* z02g  = ws + OFF_Z02;
  float* t2g   = ws + OFF_T2G;
  float* Yp    = ws + OFF_YP;
  float* Y2p   = ws + OFF_Y2P;
  float* ctxP  = ws + OFF_CTXP;
  float* denS  = ws + OFF_DENS;
  float* s1s   = ws + OFF_S1S;
  float* s2s   = ws + OFF_S2S;
  unsigned* J1     = (unsigned*)(ws + OFF_J1);
  unsigned* J2     = (unsigned*)(ws + OFF_J2);
  unsigned* bflags = (unsigned*)(ws + OFF_FLAGS);

  __shared__ float sh_xin[HS], sh_h[HS], sh_vec[HS], sh_aux[HS];
  __shared__ float sh_q[128], sh_p[64], sh_t1[16];
  __shared__ float sh_red[24], sh_den[4];

  const int bid = blockIdx.x, tid = threadIdx.x;
  const int w = tid >> 6, lane = tid & 63;
  unsigned gen = 1;

  // prefetch register files (bf16 ones held as ushort)
  float pZx[8], pZh[8];                 // H1 z1 rows (bid<64), f32
  float pZx2[8], pZh2[8];               // z0/z2 rows (bid<32 | bid>=160), f32
  unsigned short pWc[2][8], pWq[16];    // H2 (bid<32)
  unsigned short pK[8][2], pV[16];      // H3 attn (32<=bid<160)
  unsigned short pCa[2][8];             // H4 (bid<32)
  unsigned short pF1[8], pW2[8];        // H5 (all)

  auto pfH1 = [&](int l) {
    if (bid < 64) {
      const float* wxr = Wx + (((size_t)l*3 + 1)*HS + bid*8 + w)*HS;
      const float* whr = Wh + (((size_t)l*3 + 1)*HS + bid*8 + w)*HS;
#pragma unroll
      for (int k = 0; k < 8; ++k) { pZx[k] = wxr[lane+64*k]; pZh[k] = whr[lane+64*k]; }
    }
  };
  auto pfH2 = [&](int l) {
    if (bid < 32) {
#pragma unroll
      for (int rr = 0; rr < 2; ++rr) {
        const unsigned short* wr = Wcomb + ((size_t)l*HS + bid*16 + w*2 + rr)*HS;
#pragma unroll
        for (int k = 0; k < 8; ++k) pWc[rr][k] = wr[lane+64*k];
      }
#pragma unroll
      for (int r = 0; r < 16; ++r)
        pWq[r] = WqT[((size_t)l*HS + bid*16 + r)*HS + tid];
    }
  };
  auto pfH3 = [&](int l) {
    if (bid >= 32 && bid < 160) {
      const int b2 = bid - 32, h = b2 >> 5, mseg = b2 & 31;
#pragma unroll
      for (int rr = 0; rr < 8; ++rr) {
        const unsigned short* kr = Kb + ((size_t)l*MMEM + mseg*64 + w*8 + rr)*HS + h*128;
        pK[rr][0] = kr[lane]; pK[rr][1] = kr[lane+64];
      }
#pragma unroll
      for (int ml = 0; ml < 16; ++ml)
        pV[ml] = Vb[((size_t)l*MMEM + mseg*64 + (tid>>7)*16 + ml)*HS + h*128 + (tid & 127)];
    }
  };
  auto pfZ = [&](int l) {
    if (bid < 32 || bid >= 160) {
      const int zb = (bid < 32) ? bid : bid - 128;
      const int rowid = zb*8 + w;
      const int g = (rowid < 512) ? 0 : 2;
      const int f = rowid & 511;
      const float* wxr = Wx + (((size_t)l*3 + g)*HS + f)*HS;
      const float* whr = Wh + (((size_t)l*3 + g)*HS + f)*HS;
#pragma unroll
      for (int k = 0; k < 8; ++k) { pZx2[k] = wxr[lane+64*k]; pZh2[k] = whr[lane+64*k]; }
    }
  };
  auto pfH4 = [&](int l) {
    if (bid < 32) {
#pragma unroll
      for (int rr = 0; rr < 2; ++rr) {
        const unsigned short* wr = CaWob + ((size_t)l*HS + bid*16 + w*2 + rr)*HS;
#pragma unroll
        for (int k = 0; k < 8; ++k) pCa[rr][k] = wr[lane+64*k];
      }
    }
  };
  auto pfH5 = [&](int l) {
    const unsigned short* wr = F1b + ((size_t)l*FFD + bid*8 + w)*HS;
#pragma unroll
    for (int k = 0; k < 8; ++k) pF1[k] = wr[lane+64*k];
#pragma unroll
    for (int r = 0; r < 8; ++r)
      pW2[r] = W2T[((size_t)l*FFD + bid*8 + r)*HS + tid];
  };

  // fused LSTM update for step s-1; executed by blocks < 64 only
  auto do_update = [&](int ip, int parp, float& xn, float& cn) {
    const int j = tid;
    float t2v = ald(t2g + j);
    float z0  = ald(z02g + j);
    float z2  = ald(z02g + HS + j);
    float y2 = 0;
#pragma unroll
    for (int p = 0; p < 8; ++p) y2 += ald(Y2p + (size_t)p*HS + j);
    slotred32(s2s, sh_red, 16, w, lane);
    __syncthreads();
    float m2 = sh_red[16]*INV512;
    float r2 = rsqrtf(sh_red[17]*INV512 - m2*m2 + 1e-5f);
    float x2 = (t2v-m2)*r2*lnG[(ip*3+1)*HS+j] + lnB[(ip*3+1)*HS+j];
    float t3 = x2 + y2 + ffB2[ip*HS + j];
    float s_ = t3, q_ = t3*t3;
#pragma unroll
    for (int m = 32; m; m >>= 1) { s_ += __shfl_xor(s_, m); q_ += __shfl_xor(q_, m); }
    if (lane == 0) { sh_red[w] = s_; sh_red[8+w] = q_; }
    __syncthreads();
    if (tid == 0) {
      float a = 0, b = 0;
#pragma unroll
      for (int k = 0; k < 8; ++k) { a += sh_red[k]; b += sh_red[8+k]; }
      sh_red[0] = a; sh_red[1] = b;
    }
    __syncthreads();
    float m3 = sh_red[0]*INV512;
    float r3 = rsqrtf(sh_red[1]*INV512 - m3*m3 + 1e-5f);
    float d  = (t3-m3)*r3*lnG[(ip*3+2)*HS+j] + lnB[(ip*3+2)*HS+j];
    float cp = ald(cG + (parp*LNUM + ip)*HS + j);
    float ft = sigm(cp - d);
    float it = sigm(z0);
    float gt = tanhf(z2);
    cn = ft*cp + it*gt;
    xn = tanhf(cn);
  };

  pfH1(0); pfH2(0); pfH3(0);

  for (int s = 0; s < TT*LNUM; ++s) {
    const int t = s >> 2, i = s & 3;
    const int par = t & 1;
    const unsigned jv = (unsigned)(s + 1);
    // ---------- H1 window: update(s-1) + z1 matvec (0-63); zeroers (64-66) ----------
    if (bid < 64) {
      float xn = 0.f, cn = 0.f;
      if (s > 0) {
        const int ip = (s-1) & 3, tp = (s-1) >> 2, parp = tp & 1;
        if (bid == 0 || i > 0) {
          do_update(ip, parp, xn, cn);
          if (bid == 0) {
            ast(hG + ((parp^1)*LNUM + ip)*HS + tid, xn);
            ast(cG + ((parp^1)*LNUM + ip)*HS + tid, cn);
            if (ip == 3) out[tp*HS + tid] = xn;
          }
        }
      }
      float xv = (i == 0) ? x[t*HS + tid] : xn;
      sh_xin[tid] = xv;
      sh_h[tid]   = ald(hG + (par*LNUM + i)*HS + tid);
      if (bid == 0) ast(xing + tid, xv);
      __syncthreads();
      const int f = bid*8 + w;
      float acc = 0;
#pragma unroll
      for (int k = 0; k < 8; ++k) {
        int e = lane + 64*k;
        acc += pZx[k]*sh_xin[e] + pZh[k]*sh_h[e];
      }
      acc = wred(acc);
      if (lane == 0) ast(z1g + f, acc + bx[(i*3+1)*HS + f] + bh[(i*3+1)*HS + f]);
      jflag(J1, bid, jv);
    } else if (bid == 64) {
#pragma unroll
      for (int p = 0; p < 4; ++p) ast(Yp + (size_t)p*HS + tid, 0.f);
      jflag(J1, 64, jv);
    } else if (bid == 65) {
#pragma unroll
      for (int p = 0; p < 8; ++p) ast(ctxP + (size_t)p*HS + tid, 0.f);
    } else if (bid == 66) {
      jwait_pf(J1, 65, jv, [&]{});
#pragma unroll
      for (int p = 0; p < 8; ++p) ast(Y2p + (size_t)p*HS + tid, 0.f);
    }
    // ---------- J1 -> H2 (blocks 0-31): t1 + deferred q + stats1 slots ----------
    if (bid < 32) {
      jwait_pf(J1, 65, jv, [&]{});
      sh_vec[tid] = sigm(ald(z1g + tid));  // f0
      __syncthreads();
#pragma unroll
      for (int rr = 0; rr < 2; ++rr) {
        const int r = w*2 + rr, j = bid*16 + r;
        float acc = 0;
#pragma unroll
        for (int k = 0; k < 8; ++k) acc += bf2f(pWc[rr][k])*sh_vec[lane + 64*k];
        acc = wred(acc);
        if (lane == 0) {
          float t1v = sh_vec[j] + acc + csag[i*HS + j];
          sh_t1[r]  = t1v;
          sh_aux[r] = t1v;
        }
      }
      __syncthreads();
      {
        float yl = 0;
#pragma unroll
        for (int r = 0; r < 16; ++r) yl += sh_aux[r] * bf2f(pWq[r]);
        atomicAdd(&Yp[(size_t)(bid & 3)*HS + tid], yl);
      }
      if (w == 0 && lane < 16) {
        float v = sh_aux[lane], s_ = v, q_ = v*v;
#pragma unroll
        for (int m = 8; m; m >>= 1) { s_ += __shfl_xor(s_, m); q_ += __shfl_xor(q_, m); }
        if (lane == 0) { ast(s1s + bid*2, s_); ast(s1s + bid*2 + 1, q_); }
      }
    }
    barrier_pf(bflags, gen, [&]{ pfZ(i); pfH4(i); pfH5(i); });
    // ---------- H3 window: attention (32-159) | z0/z2 (0-31, 160-255) ----------
    if (bid >= 32 && bid < 160) {
      const int b2 = bid - 32, h = b2 >> 5, mseg = b2 & 31;
      slotred32(s1s, sh_red, 18, w, lane);
      __syncthreads();
      if (tid < 128) {
        float m1 = sh_red[18]*INV512;
        float r1 = rsqrtf(sh_red[19]*INV512 - m1*m1 + 1e-5f);
        int f = h*128 + tid;
        float Ysum = 0;
#pragma unroll
        for (int p = 0; p < 4; ++p) Ysum += ald(Yp + (size_t)p*HS + f);
        sh_q[tid] = r1*(Ysum - m1*sqg[i*HS + f]) + cbqg[i*HS + f];
      }
      __syncthreads();
#pragma unroll
      for (int rr = 0; rr < 8; ++rr) {
        float acc = sh_q[lane]*bf2f(pK[rr][0]) + sh_q[lane+64]*bf2f(pK[rr][1]);
        acc = wred(acc);
        if (lane == 0) sh_p[w*8 + rr] = __expf(acc * QSCALE);
      }
      __syncthreads();
      {
        const int d = tid & 127, mg = tid >> 7;
        float acc = 0;
#pragma unroll
        for (int ml = 0; ml < 16; ++ml) acc += sh_p[mg*16 + ml] * bf2f(pV[ml]);
        atomicAdd(&ctxP[(size_t)((b2 & 1)*4 + mg)*HS + h*128 + d], acc);
      }
      if (w == 0) {
        float v = wred(sh_p[lane]);
        if (lane == 0) ast(denS + h*32 + mseg, v);
      }
      jflag(J2, b2, jv);
    } else {
      const int zb = (bid < 32) ? bid : bid - 128;
      if (bid >= 160) {
        sh_xin[tid] = ald(xing + tid);
        sh_h[tid]   = ald(hG + (par*LNUM + i)*HS + tid);
      }
      __syncthreads();
      const int rowid = zb*8 + w;
      const int g = (rowid < 512) ? 0 : 2;
      const int f = rowid & 511;
      float acc = 0;
#pragma unroll
      for (int k = 0; k < 8; ++k) {
        int e = lane + 64*k;
        acc += pZx2[k]*sh_xin[e] + pZh2[k]*sh_h[e];
      }
      acc = wred(acc);
      if (lane == 0) ast(z02g + (g ? HS : 0) + f, acc + bx[(i*3+g)*HS + f] + bh[(i*3+g)*HS + f]);
      // ---------- J2 -> H4 (blocks 0-31): t2 + stats2 slots ----------
      if (bid < 32) {
        jwait_pf(J2, 128, jv, [&]{});
        slotred32(s1s, sh_red, 18, w, lane);
        if (w >= 4) {
          float v = (lane < 32) ? ald(denS + (w-4)*32 + lane) : 0.f;
#pragma unroll
          for (int m = 16; m; m >>= 1) v += __shfl_xor(v, m);
          if (lane == 0) sh_den[w-4] = v;
        }
        __syncthreads();
        const float m1 = sh_red[18]*INV512;
        const float r1 = rsqrtf(sh_red[19]*INV512 - m1*m1 + 1e-5f);
        {
          float c = 0;
#pragma unroll
          for (int p = 0; p < 8; ++p) c += ald(ctxP + (size_t)p*HS + tid);
          sh_vec[tid] = c / sh_den[tid >> 7];
        }
        __syncthreads();
#pragma unroll
        for (int rr = 0; rr < 2; ++rr) {
          const int r = w*2 + rr, j = bid*16 + r;
          float a2 = 0;
#pragma unroll
          for (int k = 0; k < 8; ++k) a2 += bf2f(pCa[rr][k])*sh_vec[lane + 64*k];
          a2 = wred(a2);
          if (lane == 0) {
            float x1 = (sh_t1[r]-m1)*r1*lnG[(i*3)*HS + j] + lnB[(i*3)*HS + j];
            float t2v = x1 + a2 + caBo[i*HS + j];
            ast(t2g + j, t2v);
            sh_aux[r] = t2v;
          }
        }
        __syncthreads();
        if (w == 0 && lane < 16) {
          float v = sh_aux[lane], s_ = v, q_ = v*v;
#pragma unroll
          for (int m = 8; m; m >>= 1) { s_ += __shfl_xor(s_, m); q_ += __shfl_xor(q_, m); }
          if (lane == 0) { ast(s2s + bid*2, s_); ast(s2s + bid*2 + 1, q_); }
        }
      }
    }
    barrier_pf(bflags, gen+1, [&]{ const int nl = (s+1) & 3; pfH1(nl); pfH2(nl); pfH3(nl); });
    // ---------- H5: all blocks: ff1 = relu(W1@x2+b1); Y2 plane += W2T@ff1 ----------
    {
      slotred32(s2s, sh_red, 16, w, lane);
      __syncthreads();
      const float m2 = sh_red[16]*INV512;
      const float r2 = rsqrtf(sh_red[17]*INV512 - m2*m2 + 1e-5f);
      sh_vec[tid] = (ald(t2g + tid)-m2)*r2*lnG[(i*3+1)*HS + tid] + lnB[(i*3+1)*HS + tid];
      __syncthreads();
      const int kk = bid*8 + w;
      float acc = 0;
#pragma unroll
      for (int k = 0; k < 8; ++k) acc += bf2f(pF1[k])*sh_vec[lane + 64*k];
      acc = wred(acc);
      if (lane == 0) sh_aux[w] = fmaxf(acc + ffB1[i*FFD + kk], 0.f);
      __syncthreads();
      float yl = 0;
#pragma unroll
      for (int r = 0; r < 8; ++r) yl += sh_aux[r] * bf2f(pW2[r]);
      atomicAdd(&Y2p[(size_t)(bid & 7)*HS + tid], yl);
    }
    barrier_pf(bflags, gen+2, [&]{});
    gen += 3;
  }

  // ---------- epilogue: final update (t=127, i=3) + output assembly ----------
  if (bid == 0) {
    float xn, cn;
    do_update(3, 1, xn, cn);
    out[127*HS + tid] = xn;
    out[TT*HS + 3*HS + tid] = xn;                 // h_T[3]
    out[TT*HS + LNUM*HS + 3*HS + tid] = cn;       // c_T[3]
#pragma unroll
    for (int ii = 0; ii < 3; ++ii) {
      out[TT*HS + ii*HS + tid]            = ald(hG + (0*LNUM + ii)*HS + tid);
      out[TT*HS + LNUM*HS + ii*HS + tid]  = ald(cG + (0*LNUM + ii)*HS + tid);
    }
  }
}

// ---------------- host launcher ----------------
extern "C" void kernel_launch(void* const* d_in, const int* in_sizes, int n_in,
                              void* d_out, int out_size, void* d_ws, size_t ws_size,
                              hipStream_t stream) {
  const float* x      = (const float*)d_in[0];
  const float* hist   = (const float*)d_in[1];
  const float* Wx     = (const float*)d_in[2];
  const float* bx     = (const float*)d_in[3];
  const float* Wh     = (const float*)d_in[4];
  const float* bh     = (const float*)d_in[5];
  const float* saWin  = (const float*)d_in[6];
  const float* saBin  = (const float*)d_in[7];
  const float* saWo   = (const float*)d_in[8];
  const float* saBo   = (const float*)d_in[9];
  const float* caWin  = (const float*)d_in[10];
  const float* caBin  = (const float*)d_in[11];
  const float* caWo   = (const float*)d_in[12];
  const float* caBo   = (const float*)d_in[13];
  const float* ffW1   = (const float*)d_in[14];
  const float* ffB1   = (const float*)d_in[15];
  const float* ffW2   = (const float*)d_in[16];
  const float* ffB2   = (const float*)d_in[17];
  const float* lnG    = (const float*)d_in[18];
  const float* lnB    = (const float*)d_in[19];
  float* ws  = (float*)d_ws;
  float* out = (float*)d_out;

  hipMemsetAsync((char*)d_ws + OFF_STATE*sizeof(float), 0,
                 (WS_TOTAL - OFF_STATE)*sizeof(float), stream);

  kv_gemm<<<dim3(MMEM/64, HS/64, LNUM), 256, 0, stream>>>(
      hist, caWin, caBin, (unsigned short*)(ws + OFF_KBF), HS);
  kv_gemm<<<dim3(MMEM/64, HS/64, LNUM), 256, 0, stream>>>(
      hist, caWin, caBin, (unsigned short*)(ws + OFF_VBF), 2*HS);
  wcomb_gemm<<<dim3(HS/64, HS/64, LNUM), 256, 0, stream>>>(
      saWo, saWin, (unsigned short*)(ws + OFF_WCOMBBF));
  csa_kernel<<<(LNUM*HS)/4, 256, 0, stream>>>(saWo, saBin, saBo, ws + OFF_CSA);
  transpose_scale_bf<<<dim3(HS/32, HS/32, LNUM), 256, 0, stream>>>(
      caWin, (size_t)(3*HS)*HS, HS, HS, lnG, (size_t)(3*HS),
      (unsigned short*)(ws + OFF_WQTBF), (size_t)HS*HS);
  sqcbq_kernel<<<(LNUM*HS)/4, 256, 0, stream>>>(caWin, caBin, lnG, lnB, ws + OFF_SQ, ws + OFF_CBQ);
  transpose_scale_bf<<<dim3(FFD/32, HS/32, LNUM), 256, 0, stream>>>(
      ffW2, (size_t)HS*FFD, HS, FFD, nullptr, 0,
      (unsigned short*)(ws + OFF_W2TBF), (size_t)FFD*HS);
  bf16_copy<<<2048, 256, 0, stream>>>(ffW1, (unsigned short*)(ws + OFF_FFW1BF),
                                      (size_t)LNUM*FFD*HS);
  bf16_copy<<<1024, 256, 0, stream>>>(caWo, (unsigned short*)(ws + OFF_CAWOBF),
                                      (size_t)LNUM*HS*HS);

  seq_kernel<<<NB, NT, 0, stream>>>(x, Wx, bx, Wh, bh, caBo,
                                    ffB1, ffB2, lnG, lnB, ws, out);
}